// Round 11
// baseline (296.010 us; speedup 1.0000x reference)
//
#include <hip/hip_runtime.h>

#define N_NODES 100000
#define N_EDGES 1600000

#define NBK 782    // row buckets of 128 rows: ceil(100000/128)
#define EPB 8192   // edges per binA block
#define NBA 196    // binA blocks: 196*8192 = 1,605,632 >= N_EDGES
#define CAPE 4096  // LDS edge-stage capacity in binB (mean bucket = 2047, sigma ~45)

typedef __attribute__((ext_vector_type(8))) short short8;
typedef __attribute__((ext_vector_type(4))) float f32x4;

__device__ __forceinline__ ushort f2bf(float f) {
    uint u = __float_as_uint(f);
    return (ushort)((u + 0x7fff + ((u >> 16) & 1)) >> 16);   // RNE
}
__device__ __forceinline__ float bflo(uint p) { return __uint_as_float(p << 16); }
__device__ __forceinline__ float bfhi(uint p) { return __uint_as_float(p & 0xffff0000u); }

// ---------------- CSR build phase A (device body; fused with layer-1 GEMM) ----------

__device__ void binA_body(int bid, const int* __restrict__ row,
                          const int* __restrict__ col, const float* __restrict__ vals,
                          int2* __restrict__ tmp, int* __restrict__ gcount,
                          int* __restrict__ offT) {
    __shared__ int h[NBK];
    __shared__ int cur[NBK];
    __shared__ int wpart[16];
    int t = threadIdx.x;
    int lane = t & 63;
    int base = bid * EPB;

    // stage 8 edges/thread in registers (row/col/vals each read exactly once)
    int rr[8], cc[8];
    float vv[8];
#pragma unroll
    for (int u = 0; u < 8; ++u) {
        int e = base + u * 1024 + t;
        bool ok = (e < N_EDGES);
        rr[u] = ok ? row[e] : -1;
        cc[u] = ok ? col[e] : 0;
        vv[u] = ok ? vals[e] : 0.f;
    }

    if (t < NBK) h[t] = 0;
    __syncthreads();
#pragma unroll
    for (int u = 0; u < 8; ++u)
        if (rr[u] >= 0) atomicAdd(&h[rr[u] >> 7], 1);
    __syncthreads();
    int hv = (t < NBK) ? h[t] : 0;
    if (hv) atomicAdd(&gcount[t], hv);

    // wave-shuffle inclusive scan over thread order (h is zero past NBK)
    int v = hv;
    for (int off = 1; off < 64; off <<= 1) {
        int u2 = __shfl_up(v, off);
        if (lane >= off) v += u2;
    }
    if (lane == 63) wpart[t >> 6] = v;
    __syncthreads();
    if (t == 0) {
        int acc = 0;
#pragma unroll
        for (int i = 0; i < 16; ++i) { int w = wpart[i]; wpart[i] = acc; acc += w; }
    }
    __syncthreads();
    v += wpart[t >> 6];                      // inclusive prefix over h[0..t]
    if (t < NBK) {
        int ex = v - hv;
        cur[t] = ex;
        offT[t * NBA + bid] = ex;
    }
    if (t == NBK - 1) offT[NBK * NBA + bid] = v;   // row NBK = edges in block
    __syncthreads();
    // scatter into block-private region, grouped by bucket
#pragma unroll
    for (int u = 0; u < 8; ++u) {
        if (rr[u] >= 0) {
            int p = atomicAdd(&cur[rr[u] >> 7], 1);
            int2 w;
            w.x = ((rr[u] & 127) << 17) | cc[u];   // 7-bit row-in-bucket | 17-bit col
            w.y = __float_as_int(vv[u]);
            tmp[base + p] = w;
        }
    }
}

// ---------------- layer-1 GEMM body (fp32 A converted in-register; 16 waves) --------
// Y[r,0..128) = bf16( X[r,:] @ Wt1^T + b1 ). 256 rows per 1024-thread block.

__device__ void gemmA_body(int bid, const float* __restrict__ Xf,
                           const ushort* __restrict__ Wt,
                           const float* __restrict__ bias, ushort* __restrict__ Y) {
    int wv = threadIdx.x >> 6;               // 0..15
    int l = threadIdx.x & 63;
    int lg = l >> 4, lm = l & 15;
    int rbase = bid * 256 + wv * 16;

    int arow = rbase + lm;
    if (arow > N_NODES - 1) arow = N_NODES - 1;     // clamp (stores predicated)

    f32x4 acc[8];
#pragma unroll
    for (int n = 0; n < 8; n++) acc[n] = (f32x4){0.f, 0.f, 0.f, 0.f};

#pragma unroll
    for (int kk = 0; kk < 4; ++kk) {
        const float* ap = Xf + (size_t)arow * 128 + kk * 32 + lg * 8;
        float4 u = *(const float4*)ap;
        float4 v = *(const float4*)(ap + 4);
        short8 a = (short8){(short)f2bf(u.x), (short)f2bf(u.y), (short)f2bf(u.z),
                            (short)f2bf(u.w), (short)f2bf(v.x), (short)f2bf(v.y),
                            (short)f2bf(v.z), (short)f2bf(v.w)};
#pragma unroll
        for (int n = 0; n < 8; ++n) {
            short8 b = *(const short8*)(Wt + (size_t)(n * 16 + lm) * 128 + kk * 32 + lg * 8);
            acc[n] = __builtin_amdgcn_mfma_f32_16x16x32_bf16(a, b, acc[n], 0, 0, 0);
        }
    }

    int r0 = rbase + lg * 4;
#pragma unroll
    for (int n = 0; n < 8; ++n) {
        int c = n * 16 + lm;
        float bj = bias[c];
#pragma unroll
        for (int i = 0; i < 4; ++i) {
            int r = r0 + i;
            if (r < N_NODES) Y[(size_t)r * 128 + c] = f2bf(acc[n][i] + bj);
        }
    }
}

// fused dispatch: blocks [0,NBA) run binA; blocks [NBA, NBA+391) run layer-1 GEMM.
__global__ void __launch_bounds__(1024) fusedA_k(const int* __restrict__ row,
                                                 const int* __restrict__ col,
                                                 const float* __restrict__ vals,
                                                 int2* __restrict__ tmp,
                                                 int* __restrict__ gcount,
                                                 int* __restrict__ offT,
                                                 const float* __restrict__ x,
                                                 const ushort* __restrict__ Wt1,
                                                 const float* __restrict__ b1,
                                                 ushort* __restrict__ g) {
    if (blockIdx.x < NBA)
        binA_body(blockIdx.x, row, col, vals, tmp, gcount, offT);
    else
        gemmA_body(blockIdx.x - NBA, x, Wt1, b1, g);
}

// Phase B: one block per bucket. Computes its own bstart (prefix sum of gcount[0..b))
// via strided read + wave reduction — bscan dispatch eliminated. 16-lane group per
// segment loads coalesced, histograms, packs into ebuf; pass 2 scatters flat.

__global__ void __launch_bounds__(256) binB_k(const int2* __restrict__ tmp,
                                              const int* __restrict__ offT,
                                              const int* __restrict__ gcount,
                                              int* __restrict__ rowptr,
                                              int2* __restrict__ ep) {
    __shared__ int goff[NBA];
    __shared__ int scnt[NBA];
    __shared__ int sdst[NBA];
    __shared__ int h[128];
    __shared__ int cur[128];
    __shared__ int2 ebuf[CAPE];
    __shared__ int wpart[4];
    __shared__ int wq[4];
    __shared__ int hp;
    int b = blockIdx.x, t = threadIdx.x;
    int lane = t & 63;

    // bstart[b] = sum gcount[0..b) (strided partial + wave reduce)
    int part = 0;
    for (int i = t; i < b; i += 256) part += gcount[i];
#pragma unroll
    for (int off = 1; off < 64; off <<= 1) part += __shfl_xor(part, off);
    if (lane == 0) wq[t >> 6] = part;
    if (b == 0 && t == 0) rowptr[N_NODES] = N_EDGES;

    int c = 0;
    if (t < NBA) {
        int o0 = offT[b * NBA + t];
        int o1 = offT[(b + 1) * NBA + t];
        c = o1 - o0;
        goff[t] = t * EPB + o0;
        scnt[t] = c;
    }
    // exclusive scan of segment counts (wave shuffle, 256 threads)
    int v = c;
    for (int off = 1; off < 64; off <<= 1) {
        int u = __shfl_up(v, off);
        if (lane >= off) v += u;
    }
    if (lane == 63) wpart[t >> 6] = v;
    if (t < 128) h[t] = 0;
    __syncthreads();
    if (t == 0) {
        int acc = 0;
#pragma unroll
        for (int i = 0; i < 4; ++i) { int w = wpart[i]; wpart[i] = acc; acc += w; }
    }
    __syncthreads();
    v += wpart[t >> 6];
    if (t < NBA) sdst[t] = v - c;
    __syncthreads();

    // pass 1: 16-lane group per segment: coalesced load, LDS hist, pack into ebuf
    int grp = t >> 4, gl = t & 15;            // 16 groups of 16 lanes
    for (int s = grp; s < NBA; s += 16) {
        int n = scnt[s], go = goff[s], dd = sdst[s];
        for (int i = gl; i < n; i += 16) {
            int2 e = tmp[go + i];
            atomicAdd(&h[e.x >> 17], 1);
            ebuf[dd + i] = e;
        }
    }
    __syncthreads();
    // exclusive scan over 128 bins (2 waves + 1 partial)
    int hv = (t < 128) ? h[t] : 0;
    int sv = hv;
    for (int off = 1; off < 64; off <<= 1) {
        int u = __shfl_up(sv, off);
        if (lane >= off) sv += u;
    }
    if (t == 63) hp = sv;
    __syncthreads();
    int bs = wq[0] + wq[1] + wq[2] + wq[3];
    if (t < 128) {
        int inc = sv + ((t >= 64) ? hp : 0);
        int ex = inc - hv;
        cur[t] = ex;
        int r = (b << 7) + t;
        if (r < N_NODES) rowptr[r] = bs + ex;
    }
    __syncthreads();
    // pass 2: flat scatter from packed ebuf to final CSR positions
    int T = sdst[NBA - 1] + scnt[NBA - 1];
    for (int j = t; j < T; j += 256) {
        int2 e = ebuf[j];
        int p = atomicAdd(&cur[e.x >> 17], 1);
        int2 w;
        w.x = e.x & 0x1ffff;
        w.y = e.y;
        ep[bs + p] = w;
    }
}

// ---------------- converts ----------------

// transpose-convert all three weight matrices: Wt[n][k] = bf16(W[k][n]).
// Also zeroes gcount (this kernel launches FIRST).
__global__ void wcvt_k(const float* __restrict__ W1, const float* __restrict__ W2,
                       const float* __restrict__ W3, ushort* __restrict__ Wt1,
                       ushort* __restrict__ Wt2, ushort* __restrict__ Wt3,
                       int* __restrict__ gcount) {
    int i = blockIdx.x * 256 + threadIdx.x;
    if (i < NBK) gcount[i] = 0;
    if (i < 16384) {
        int n = i >> 7, k = i & 127;
        Wt1[i] = f2bf(W1[k * 128 + n]);
        Wt2[i] = f2bf(W2[k * 128 + n]);
    }
    if (i < 8192) {
        int n = i >> 7, k = i & 127;
        Wt3[i] = f2bf(W3[k * 64 + n]);
    }
}

// ---------------- GEMM (bf16 in): Y[r, 0..DN) = bf16( Xb[r,:] @ Wt^T + bias ) -------

template <int DN>
__global__ void __launch_bounds__(256) gemm_k(const ushort* __restrict__ Xb,
                                              const ushort* __restrict__ Wt,
                                              const float* __restrict__ bias,
                                              ushort* __restrict__ Y) {
    constexpr int NT = DN / 16;
    int wv = threadIdx.x >> 6;
    int l = threadIdx.x & 63;
    int lg = l >> 4, lm = l & 15;
    int rbase = blockIdx.x * 64 + wv * 16;

    int arow = rbase + lm;
    if (arow > N_NODES - 1) arow = N_NODES - 1;     // clamp (stores predicated)

    f32x4 acc[NT];
#pragma unroll
    for (int n = 0; n < NT; n++) acc[n] = (f32x4){0.f, 0.f, 0.f, 0.f};

#pragma unroll
    for (int kk = 0; kk < 4; ++kk) {
        short8 a = *(const short8*)(Xb + (size_t)arow * 128 + kk * 32 + lg * 8);
#pragma unroll
        for (int n = 0; n < NT; ++n) {
            short8 b = *(const short8*)(Wt + (size_t)(n * 16 + lm) * 128 + kk * 32 + lg * 8);
            acc[n] = __builtin_amdgcn_mfma_f32_16x16x32_bf16(a, b, acc[n], 0, 0, 0);
        }
    }

    int r0 = rbase + lg * 4;
#pragma unroll
    for (int n = 0; n < NT; ++n) {
        int c = n * 16 + lm;
        float bj = bias[c];
#pragma unroll
        for (int i = 0; i < 4; ++i) {
            int r = r0 + i;
            if (r < N_NODES) Y[(size_t)r * DN + c] = f2bf(acc[n][i] + bj);
        }
    }
}

// ---------------- SpMM (CSR; one 16-lane group per row; ep staged via LDS) -----------

#define SPMM_BODY(EPREAD)                                                     \
    if (D == 128) {                                                           \
        const uint4* xp = (const uint4*)xb;                                   \
        float a0 = 0.f, a1 = 0.f, a2 = 0.f, a3 = 0.f;                         \
        float a4 = 0.f, a5 = 0.f, a6 = 0.f, a7 = 0.f;                         \
        int i = s;                                                            \
        for (; i + 4 <= e; i += 4) {                                          \
            int2 e0 = EPREAD(i), e1 = EPREAD(i + 1);                          \
            int2 e2 = EPREAD(i + 2), e3 = EPREAD(i + 3);                      \
            uint4 x0 = xp[e0.x * 16 + hl];                                    \
            uint4 x1 = xp[e1.x * 16 + hl];                                    \
            uint4 x2 = xp[e2.x * 16 + hl];                                    \
            uint4 x3 = xp[e3.x * 16 + hl];                                    \
            float v0 = __int_as_float(e0.y), v1 = __int_as_float(e1.y);       \
            float v2 = __int_as_float(e2.y), v3 = __int_as_float(e3.y);       \
            a0 = fmaf(v0, bflo(x0.x), a0); a1 = fmaf(v0, bfhi(x0.x), a1);     \
            a2 = fmaf(v0, bflo(x0.y), a2); a3 = fmaf(v0, bfhi(x0.y), a3);     \
            a4 = fmaf(v0, bflo(x0.z), a4); a5 = fmaf(v0, bfhi(x0.z), a5);     \
            a6 = fmaf(v0, bflo(x0.w), a6); a7 = fmaf(v0, bfhi(x0.w), a7);     \
            a0 = fmaf(v1, bflo(x1.x), a0); a1 = fmaf(v1, bfhi(x1.x), a1);     \
            a2 = fmaf(v1, bflo(x1.y), a2); a3 = fmaf(v1, bfhi(x1.y), a3);     \
            a4 = fmaf(v1, bflo(x1.z), a4); a5 = fmaf(v1, bfhi(x1.z), a5);     \
            a6 = fmaf(v1, bflo(x1.w), a6); a7 = fmaf(v1, bfhi(x1.w), a7);     \
            a0 = fmaf(v2, bflo(x2.x), a0); a1 = fmaf(v2, bfhi(x2.x), a1);     \
            a2 = fmaf(v2, bflo(x2.y), a2); a3 = fmaf(v2, bfhi(x2.y), a3);     \
            a4 = fmaf(v2, bflo(x2.z), a4); a5 = fmaf(v2, bfhi(x2.z), a5);     \
            a6 = fmaf(v2, bflo(x2.w), a6); a7 = fmaf(v2, bfhi(x2.w), a7);     \
            a0 = fmaf(v3, bflo(x3.x), a0); a1 = fmaf(v3, bfhi(x3.x), a1);     \
            a2 = fmaf(v3, bflo(x3.y), a2); a3 = fmaf(v3, bfhi(x3.y), a3);     \
            a4 = fmaf(v3, bflo(x3.z), a4); a5 = fmaf(v3, bfhi(x3.z), a5);     \
            a6 = fmaf(v3, bflo(x3.w), a6); a7 = fmaf(v3, bfhi(x3.w), a7);     \
        }                                                                     \
        for (; i < e; ++i) {                                                  \
            int2 e0 = EPREAD(i);                                              \
            uint4 x0 = xp[e0.x * 16 + hl];                                    \
            float v0 = __int_as_float(e0.y);                                  \
            a0 = fmaf(v0, bflo(x0.x), a0); a1 = fmaf(v0, bfhi(x0.x), a1);     \
            a2 = fmaf(v0, bflo(x0.y), a2); a3 = fmaf(v0, bfhi(x0.y), a3);     \
            a4 = fmaf(v0, bflo(x0.z), a4); a5 = fmaf(v0, bfhi(x0.z), a5);     \
            a6 = fmaf(v0, bflo(x0.w), a6); a7 = fmaf(v0, bfhi(x0.w), a7);     \
        }                                                                     \
        if (RELU) {                                                           \
            a0 = fmaxf(a0, 0.f); a1 = fmaxf(a1, 0.f);                         \
            a2 = fmaxf(a2, 0.f); a3 = fmaxf(a3, 0.f);                         \
            a4 = fmaxf(a4, 0.f); a5 = fmaxf(a5, 0.f);                         \
            a6 = fmaxf(a6, 0.f); a7 = fmaxf(a7, 0.f);                         \
        }                                                                     \
        uint4 o;                                                              \
        o.x = (uint)f2bf(a0) | ((uint)f2bf(a1) << 16);                        \
        o.y = (uint)f2bf(a2) | ((uint)f2bf(a3) << 16);                        \
        o.z = (uint)f2bf(a4) | ((uint)f2bf(a5) << 16);                        \
        o.w = (uint)f2bf(a6) | ((uint)f2bf(a7) << 16);                        \
        ((uint4*)y)[w * 16 + hl] = o;                                         \
    } else {                                                                  \
        const uint2* xp = (const uint2*)xb;                                   \
        float a0 = 0.f, a1 = 0.f, a2 = 0.f, a3 = 0.f;                         \
        int i = s;                                                            \
        for (; i + 4 <= e; i += 4) {                                          \
            int2 e0 = EPREAD(i), e1 = EPREAD(i + 1);                          \
            int2 e2 = EPREAD(i + 2), e3 = EPREAD(i + 3);                      \
            uint2 x0 = xp[e0.x * 16 + hl];                                    \
            uint2 x1 = xp[e1.x * 16 + hl];                                    \
            uint2 x2 = xp[e2.x * 16 + hl];                                    \
            uint2 x3 = xp[e3.x * 16 + hl];                                    \
            float v0 = __int_as_float(e0.y), v1 = __int_as_float(e1.y);       \
            float v2 = __int_as_float(e2.y), v3 = __int_as_float(e3.y);       \
            a0 = fmaf(v0, bflo(x0.x), a0); a1 = fmaf(v0, bfhi(x0.x), a1);     \
            a2 = fmaf(v0, bflo(x0.y), a2); a3 = fmaf(v0, bfhi(x0.y), a3);     \
            a0 = fmaf(v1, bflo(x1.x), a0); a1 = fmaf(v1, bfhi(x1.x), a1);     \
            a2 = fmaf(v1, bflo(x1.y), a2); a3 = fmaf(v1, bfhi(x1.y), a3);     \
            a0 = fmaf(v2, bflo(x2.x), a0); a1 = fmaf(v2, bfhi(x2.x), a1);     \
            a2 = fmaf(v2, bflo(x2.y), a2); a3 = fmaf(v2, bfhi(x2.y), a3);     \
            a0 = fmaf(v3, bflo(x3.x), a0); a1 = fmaf(v3, bfhi(x3.x), a1);     \
            a2 = fmaf(v3, bflo(x3.y), a2); a3 = fmaf(v3, bfhi(x3.y), a3);     \
        }                                                                     \
        for (; i < e; ++i) {                                                  \
            int2 e0 = EPREAD(i);                                              \
            uint2 x0 = xp[e0.x * 16 + hl];                                    \
            float v0 = __int_as_float(e0.y);                                  \
            a0 = fmaf(v0, bflo(x0.x), a0); a1 = fmaf(v0, bfhi(x0.x), a1);     \
            a2 = fmaf(v0, bflo(x0.y), a2); a3 = fmaf(v0, bfhi(x0.y), a3);     \
        }                                                                     \
        if (RELU) {                                                           \
            a0 = fmaxf(a0, 0.f); a1 = fmaxf(a1, 0.f);                         \
            a2 = fmaxf(a2, 0.f); a3 = fmaxf(a3, 0.f);                         \
        }                                                                     \
        float4 o; o.x = a0; o.y = a1; o.z = a2; o.w = a3;                     \
        ((float4*)y)[w * 16 + hl] = o;                                        \
    }

template <int D, bool RELU>
__global__ void __launch_bounds__(256) spmm_k(const int* __restrict__ rowptr,
                                              const int2* __restrict__ ep,
                                              const ushort* __restrict__ xb,
                                              void* __restrict__ y) {
    constexpr int CAP = 1536;                  // 12 KB LDS; block mean = 256 edges
    __shared__ int2 eb[CAP];
    __shared__ int sh_s0, sh_n;
    int t = threadIdx.x;
    int g = t >> 4, hl = t & 15;
    int rbase = blockIdx.x * 16;
    int w = rbase + g;

    if (t == 0) {
        int s0 = rowptr[rbase];
        int rend = rbase + 16; if (rend > N_NODES) rend = N_NODES;
        sh_s0 = s0;
        sh_n = rowptr[rend] - s0;
    }
    __syncthreads();
    int s0 = sh_s0, n = sh_n;
    bool inlds = (n <= CAP);
    if (inlds) {
        for (int j = t; j < n; j += 256) eb[j] = ep[s0 + j];   // coalesced stage
    }
    __syncthreads();
    if (w >= N_NODES) return;
    int s = rowptr[w], e = rowptr[w + 1];

    if (inlds) {
        s -= s0; e -= s0;
#define EPL(i) eb[i]
        SPMM_BODY(EPL)
#undef EPL
    } else {                                   // overflow fallback (rare)
#define EPG(i) ep[i]
        SPMM_BODY(EPG)
#undef EPG
    }
}

// ---------------- launch ----------------

extern "C" void kernel_launch(void* const* d_in, const int* in_sizes, int n_in,
                              void* d_out, int out_size, void* d_ws, size_t ws_size,
                              hipStream_t stream) {
    const float* x    = (const float*)d_in[0];
    const float* vals = (const float*)d_in[1];
    const float* W1   = (const float*)d_in[2];
    const float* b1   = (const float*)d_in[3];
    const float* W2   = (const float*)d_in[4];
    const float* b2   = (const float*)d_in[5];
    const float* W3   = (const float*)d_in[6];
    const float* b3   = (const float*)d_in[7];
    const int* row    = (const int*)d_in[8];
    const int* col    = (const int*)d_in[9];
    float* out = (float*)d_out;

    char* ws = (char*)d_ws;
    int2*   ep     = (int2*)  (ws + 0);          // 12,800,000
    int*    rowptr = (int*)   (ws + 12800000);   // 400,004
    int*    gcount = (int*)   (ws + 13250000);   // 3,128
    ushort* Wt1    = (ushort*)(ws + 13601024);   // 32,768
    ushort* Wt2    = (ushort*)(ws + 13633792);   // 32,768
    ushort* Wt3    = (ushort*)(ws + 13666560);   // 16,384
    int*    offT   = (int*)   (ws + 13700096);   // (NBK+1)*NBA*4 = 613,872
    ushort* g64    = (ushort*)(ws + 16000000);   // 12,800,000 (layer-3 gemm out)
    ushort* g      = (ushort*)(ws + 41600000);   // 25,600,000 (gemm out; NOT tmp)
    ushort* sbuf   = (ushort*)(ws + 67200000);   // 25,600,000  (total 92.8MB)

    // tmp aliases sbuf (dead until spmm L1 writes it; binB completes before then).
    // This makes binA independent of g, enabling the binA+gemm1 fusion.
    int2* tmp = (int2*)sbuf;                     // NBA*EPB*8 = 12,845,056 <= 25.6MB

    // 1) weight converts + gcount zeroing
    hipLaunchKernelGGL(wcvt_k, dim3(64), dim3(256), 0, stream,
                       W1, W2, W3, Wt1, Wt2, Wt3, gcount);

    // 2) fused: CSR phase A (blocks 0..195) + layer-1 GEMM (blocks 196..586)
    const int GEMM1_BLKS = (N_NODES + 255) / 256;   // 391
    hipLaunchKernelGGL(fusedA_k, dim3(NBA + GEMM1_BLKS), dim3(1024), 0, stream,
                       row, col, vals, tmp, gcount, offT, x, Wt1, b1, g);

    // 3) CSR phase B (computes own bstart; bscan eliminated)
    hipLaunchKernelGGL(binB_k, dim3(NBK), dim3(256), 0, stream,
                       tmp, offT, gcount, rowptr, ep);

    const int GEMM_GRID = (N_NODES + 63) / 64;     // 1563
    const int SPMM_GRID = (N_NODES + 15) / 16;     // 6250

    // 4) spmm L1 (overwrites sbuf/tmp — build is complete)
    hipLaunchKernelGGL((spmm_k<128, true>), dim3(SPMM_GRID), dim3(256), 0, stream,
                       rowptr, ep, g, sbuf);
    // 5-6) layer 2
    hipLaunchKernelGGL((gemm_k<128>), dim3(GEMM_GRID), dim3(256), 0, stream, sbuf, Wt2, b2, g);
    hipLaunchKernelGGL((spmm_k<128, true>), dim3(SPMM_GRID), dim3(256), 0, stream,
                       rowptr, ep, g, sbuf);
    // 7-8) layer 3
    hipLaunchKernelGGL((gemm_k<64>), dim3(GEMM_GRID), dim3(256), 0, stream, sbuf, Wt3, b3, g64);
    hipLaunchKernelGGL((spmm_k<64, false>), dim3(SPMM_GRID), dim3(256), 0, stream,
                       rowptr, ep, g64, out);
}

// Round 12
// 291.827 us; speedup vs baseline: 1.0143x; 1.0143x over previous
//
#include <hip/hip_runtime.h>

#define N_NODES 100000
#define N_EDGES 1600000

#define NBK 782    // row buckets of 128 rows: ceil(100000/128)
#define EPB 8192   // edges per binA block
#define NBA 196    // binA blocks: 196*8192 = 1,605,632 >= N_EDGES
#define CAPE 4096  // LDS edge-stage capacity in binB (mean bucket = 2047, sigma ~45)

typedef __attribute__((ext_vector_type(8))) short short8;
typedef __attribute__((ext_vector_type(4))) float f32x4;

__device__ __forceinline__ ushort f2bf(float f) {
    uint u = __float_as_uint(f);
    return (ushort)((u + 0x7fff + ((u >> 16) & 1)) >> 16);   // RNE
}
__device__ __forceinline__ float bflo(uint p) { return __uint_as_float(p << 16); }
__device__ __forceinline__ float bfhi(uint p) { return __uint_as_float(p & 0xffff0000u); }

// ---------------- CSR build: two-pass counting sort by 128-row bucket ----------------
// Phase A (v2): single-pass rank trick — one atomicAdd per edge yields BOTH the
// histogram and the within-bucket rank; the scatter pass then needs NO atomics.
// (was 16 LDS atomics/thread, now 8 — binA was LDS-atomic-serialization-bound.)

__global__ void __launch_bounds__(1024) binA_k(const int* __restrict__ row,
                                               const int* __restrict__ col,
                                               const float* __restrict__ vals,
                                               int2* __restrict__ tmp,
                                               int* __restrict__ gcount,
                                               int* __restrict__ offT) {
    __shared__ int cnt[NBK];
    __shared__ int exo[NBK];
    __shared__ int wpart[16];
    int t = threadIdx.x;
    int lane = t & 63;
    int base = blockIdx.x * EPB;

    // stage 8 edges/thread in registers (row/col/vals each read exactly once)
    int rr[8], cc[8], rk[8];
    float vv[8];
#pragma unroll
    for (int u = 0; u < 8; ++u) {
        int e = base + u * 1024 + t;
        bool ok = (e < N_EDGES);
        rr[u] = ok ? row[e] : -1;
        cc[u] = ok ? col[e] : 0;
        vv[u] = ok ? vals[e] : 0.f;
    }

    if (t < NBK) cnt[t] = 0;
    __syncthreads();
#pragma unroll
    for (int u = 0; u < 8; ++u)
        if (rr[u] >= 0) rk[u] = atomicAdd(&cnt[rr[u] >> 7], 1);   // rank + histogram
    __syncthreads();
    int hv = (t < NBK) ? cnt[t] : 0;
    if (hv) atomicAdd(&gcount[t], hv);

    // wave-shuffle inclusive scan over thread order (cnt is zero past NBK)
    int v = hv;
    for (int off = 1; off < 64; off <<= 1) {
        int u2 = __shfl_up(v, off);
        if (lane >= off) v += u2;
    }
    if (lane == 63) wpart[t >> 6] = v;
    __syncthreads();
    if (t == 0) {
        int acc = 0;
#pragma unroll
        for (int i = 0; i < 16; ++i) { int w = wpart[i]; wpart[i] = acc; acc += w; }
    }
    __syncthreads();
    v += wpart[t >> 6];                      // inclusive prefix over cnt[0..t]
    if (t < NBK) {
        int ex = v - hv;
        exo[t] = ex;
        offT[t * NBA + blockIdx.x] = ex;
    }
    if (t == NBK - 1) offT[NBK * NBA + blockIdx.x] = v;  // row NBK = edges in block
    __syncthreads();
    // scatter into block-private region, grouped by bucket — NO atomics
#pragma unroll
    for (int u = 0; u < 8; ++u) {
        if (rr[u] >= 0) {
            int p = exo[rr[u] >> 7] + rk[u];
            int2 w;
            w.x = ((rr[u] & 127) << 17) | cc[u];   // 7-bit row-in-bucket | 17-bit col
            w.y = __float_as_int(vv[u]);
            tmp[base + p] = w;
        }
    }
}

// Phase B: one block per bucket. Computes its own bstart (prefix sum of gcount[0..b))
// via strided read + wave reduction. 16-lane group per segment loads coalesced,
// histograms, packs into ebuf; pass 2 scatters flat from the packed ebuf.

__global__ void __launch_bounds__(256) binB_k(const int2* __restrict__ tmp,
                                              const int* __restrict__ offT,
                                              const int* __restrict__ gcount,
                                              int* __restrict__ rowptr,
                                              int2* __restrict__ ep) {
    __shared__ int goff[NBA];
    __shared__ int scnt[NBA];
    __shared__ int sdst[NBA];
    __shared__ int h[128];
    __shared__ int cur[128];
    __shared__ int2 ebuf[CAPE];
    __shared__ int wpart[4];
    __shared__ int wq[4];
    __shared__ int hp;
    int b = blockIdx.x, t = threadIdx.x;
    int lane = t & 63;

    // bstart[b] = sum gcount[0..b) (strided partial + wave reduce)
    int part = 0;
    for (int i = t; i < b; i += 256) part += gcount[i];
#pragma unroll
    for (int off = 1; off < 64; off <<= 1) part += __shfl_xor(part, off);
    if (lane == 0) wq[t >> 6] = part;
    if (b == 0 && t == 0) rowptr[N_NODES] = N_EDGES;

    int c = 0;
    if (t < NBA) {
        int o0 = offT[b * NBA + t];
        int o1 = offT[(b + 1) * NBA + t];
        c = o1 - o0;
        goff[t] = t * EPB + o0;
        scnt[t] = c;
    }
    // exclusive scan of segment counts (wave shuffle, 256 threads)
    int v = c;
    for (int off = 1; off < 64; off <<= 1) {
        int u = __shfl_up(v, off);
        if (lane >= off) v += u;
    }
    if (lane == 63) wpart[t >> 6] = v;
    if (t < 128) h[t] = 0;
    __syncthreads();
    if (t == 0) {
        int acc = 0;
#pragma unroll
        for (int i = 0; i < 4; ++i) { int w = wpart[i]; wpart[i] = acc; acc += w; }
    }
    __syncthreads();
    v += wpart[t >> 6];
    if (t < NBA) sdst[t] = v - c;
    __syncthreads();

    // pass 1: 16-lane group per segment: coalesced load, LDS hist, pack into ebuf
    int grp = t >> 4, gl = t & 15;            // 16 groups of 16 lanes
    for (int s = grp; s < NBA; s += 16) {
        int n = scnt[s], go = goff[s], dd = sdst[s];
        for (int i = gl; i < n; i += 16) {
            int2 e = tmp[go + i];
            atomicAdd(&h[e.x >> 17], 1);
            ebuf[dd + i] = e;
        }
    }
    __syncthreads();
    // exclusive scan over 128 bins (2 waves + 1 partial)
    int hv = (t < 128) ? h[t] : 0;
    int sv = hv;
    for (int off = 1; off < 64; off <<= 1) {
        int u = __shfl_up(sv, off);
        if (lane >= off) sv += u;
    }
    if (t == 63) hp = sv;
    __syncthreads();
    int bs = wq[0] + wq[1] + wq[2] + wq[3];
    if (t < 128) {
        int inc = sv + ((t >= 64) ? hp : 0);
        int ex = inc - hv;
        cur[t] = ex;
        int r = (b << 7) + t;
        if (r < N_NODES) rowptr[r] = bs + ex;
    }
    __syncthreads();
    // pass 2: flat scatter from packed ebuf to final CSR positions
    int T = sdst[NBA - 1] + scnt[NBA - 1];
    for (int j = t; j < T; j += 256) {
        int2 e = ebuf[j];
        int p = atomicAdd(&cur[e.x >> 17], 1);
        int2 w;
        w.x = e.x & 0x1ffff;
        w.y = e.y;
        ep[bs + p] = w;
    }
}

// ---------------- converts ----------------

// transpose-convert all three weight matrices: Wt[n][k] = bf16(W[k][n]).
// Also zeroes gcount (this kernel launches FIRST).
__global__ void wcvt_k(const float* __restrict__ W1, const float* __restrict__ W2,
                       const float* __restrict__ W3, ushort* __restrict__ Wt1,
                       ushort* __restrict__ Wt2, ushort* __restrict__ Wt3,
                       int* __restrict__ gcount) {
    int i = blockIdx.x * 256 + threadIdx.x;
    if (i < NBK) gcount[i] = 0;
    if (i < 16384) {
        int n = i >> 7, k = i & 127;
        Wt1[i] = f2bf(W1[k * 128 + n]);
        Wt2[i] = f2bf(W2[k * 128 + n]);
    }
    if (i < 8192) {
        int n = i >> 7, k = i & 127;
        Wt3[i] = f2bf(W3[k * 64 + n]);
    }
}

// ---------------- GEMM: Y[r, 0..DN) = bf16( X[r,:] @ Wt^T + bias ) ----------------
// AF32: A is fp32 and converted in-register (fuses the cvtx pass into layer 1).

template <int DN, bool AF32>
__global__ void __launch_bounds__(256) gemm_k(const void* __restrict__ Xa,
                                              const ushort* __restrict__ Wt,
                                              const float* __restrict__ bias,
                                              ushort* __restrict__ Y) {
    constexpr int NT = DN / 16;
    const ushort* Xb = (const ushort*)Xa;
    const float* Xf = (const float*)Xa;
    int wv = threadIdx.x >> 6;
    int l = threadIdx.x & 63;
    int lg = l >> 4, lm = l & 15;
    int rbase = blockIdx.x * 64 + wv * 16;

    int arow = rbase + lm;
    if (arow > N_NODES - 1) arow = N_NODES - 1;     // clamp (stores predicated)

    f32x4 acc[NT];
#pragma unroll
    for (int n = 0; n < NT; n++) acc[n] = (f32x4){0.f, 0.f, 0.f, 0.f};

#pragma unroll
    for (int kk = 0; kk < 4; ++kk) {
        short8 a;
        if constexpr (AF32) {
            const float* ap = Xf + (size_t)arow * 128 + kk * 32 + lg * 8;
            float4 u = *(const float4*)ap;
            float4 v = *(const float4*)(ap + 4);
            a = (short8){(short)f2bf(u.x), (short)f2bf(u.y), (short)f2bf(u.z), (short)f2bf(u.w),
                         (short)f2bf(v.x), (short)f2bf(v.y), (short)f2bf(v.z), (short)f2bf(v.w)};
        } else {
            a = *(const short8*)(Xb + (size_t)arow * 128 + kk * 32 + lg * 8);
        }
#pragma unroll
        for (int n = 0; n < NT; ++n) {
            short8 b = *(const short8*)(Wt + (size_t)(n * 16 + lm) * 128 + kk * 32 + lg * 8);
            acc[n] = __builtin_amdgcn_mfma_f32_16x16x32_bf16(a, b, acc[n], 0, 0, 0);
        }
    }

    int r0 = rbase + lg * 4;
#pragma unroll
    for (int n = 0; n < NT; ++n) {
        int c = n * 16 + lm;
        float bj = bias[c];
#pragma unroll
        for (int i = 0; i < 4; ++i) {
            int r = r0 + i;
            if (r < N_NODES) Y[(size_t)r * DN + c] = f2bf(acc[n][i] + bj);
        }
    }
}

// ---------------- SpMM (CSR; one 16-lane group per row; ep staged via LDS) -----------

#define SPMM_BODY(EPREAD)                                                     \
    if (D == 128) {                                                           \
        const uint4* xp = (const uint4*)xb;                                   \
        float a0 = 0.f, a1 = 0.f, a2 = 0.f, a3 = 0.f;                         \
        float a4 = 0.f, a5 = 0.f, a6 = 0.f, a7 = 0.f;                         \
        int i = s;                                                            \
        for (; i + 4 <= e; i += 4) {                                          \
            int2 e0 = EPREAD(i), e1 = EPREAD(i + 1);                          \
            int2 e2 = EPREAD(i + 2), e3 = EPREAD(i + 3);                      \
            uint4 x0 = xp[e0.x * 16 + hl];                                    \
            uint4 x1 = xp[e1.x * 16 + hl];                                    \
            uint4 x2 = xp[e2.x * 16 + hl];                                    \
            uint4 x3 = xp[e3.x * 16 + hl];                                    \
            float v0 = __int_as_float(e0.y), v1 = __int_as_float(e1.y);       \
            float v2 = __int_as_float(e2.y), v3 = __int_as_float(e3.y);       \
            a0 = fmaf(v0, bflo(x0.x), a0); a1 = fmaf(v0, bfhi(x0.x), a1);     \
            a2 = fmaf(v0, bflo(x0.y), a2); a3 = fmaf(v0, bfhi(x0.y), a3);     \
            a4 = fmaf(v0, bflo(x0.z), a4); a5 = fmaf(v0, bfhi(x0.z), a5);     \
            a6 = fmaf(v0, bflo(x0.w), a6); a7 = fmaf(v0, bfhi(x0.w), a7);     \
            a0 = fmaf(v1, bflo(x1.x), a0); a1 = fmaf(v1, bfhi(x1.x), a1);     \
            a2 = fmaf(v1, bflo(x1.y), a2); a3 = fmaf(v1, bfhi(x1.y), a3);     \
            a4 = fmaf(v1, bflo(x1.z), a4); a5 = fmaf(v1, bfhi(x1.z), a5);     \
            a6 = fmaf(v1, bflo(x1.w), a6); a7 = fmaf(v1, bfhi(x1.w), a7);     \
            a0 = fmaf(v2, bflo(x2.x), a0); a1 = fmaf(v2, bfhi(x2.x), a1);     \
            a2 = fmaf(v2, bflo(x2.y), a2); a3 = fmaf(v2, bfhi(x2.y), a3);     \
            a4 = fmaf(v2, bflo(x2.z), a4); a5 = fmaf(v2, bfhi(x2.z), a5);     \
            a6 = fmaf(v2, bflo(x2.w), a6); a7 = fmaf(v2, bfhi(x2.w), a7);     \
            a0 = fmaf(v3, bflo(x3.x), a0); a1 = fmaf(v3, bfhi(x3.x), a1);     \
            a2 = fmaf(v3, bflo(x3.y), a2); a3 = fmaf(v3, bfhi(x3.y), a3);     \
            a4 = fmaf(v3, bflo(x3.z), a4); a5 = fmaf(v3, bfhi(x3.z), a5);     \
            a6 = fmaf(v3, bflo(x3.w), a6); a7 = fmaf(v3, bfhi(x3.w), a7);     \
        }                                                                     \
        for (; i < e; ++i) {                                                  \
            int2 e0 = EPREAD(i);                                              \
            uint4 x0 = xp[e0.x * 16 + hl];                                    \
            float v0 = __int_as_float(e0.y);                                  \
            a0 = fmaf(v0, bflo(x0.x), a0); a1 = fmaf(v0, bfhi(x0.x), a1);     \
            a2 = fmaf(v0, bflo(x0.y), a2); a3 = fmaf(v0, bfhi(x0.y), a3);     \
            a4 = fmaf(v0, bflo(x0.z), a4); a5 = fmaf(v0, bfhi(x0.z), a5);     \
            a6 = fmaf(v0, bflo(x0.w), a6); a7 = fmaf(v0, bfhi(x0.w), a7);     \
        }                                                                     \
        if (RELU) {                                                           \
            a0 = fmaxf(a0, 0.f); a1 = fmaxf(a1, 0.f);                         \
            a2 = fmaxf(a2, 0.f); a3 = fmaxf(a3, 0.f);                         \
            a4 = fmaxf(a4, 0.f); a5 = fmaxf(a5, 0.f);                         \
            a6 = fmaxf(a6, 0.f); a7 = fmaxf(a7, 0.f);                         \
        }                                                                     \
        uint4 o;                                                              \
        o.x = (uint)f2bf(a0) | ((uint)f2bf(a1) << 16);                        \
        o.y = (uint)f2bf(a2) | ((uint)f2bf(a3) << 16);                        \
        o.z = (uint)f2bf(a4) | ((uint)f2bf(a5) << 16);                        \
        o.w = (uint)f2bf(a6) | ((uint)f2bf(a7) << 16);                        \
        ((uint4*)y)[w * 16 + hl] = o;                                         \
    } else {                                                                  \
        const uint2* xp = (const uint2*)xb;                                   \
        float a0 = 0.f, a1 = 0.f, a2 = 0.f, a3 = 0.f;                         \
        int i = s;                                                            \
        for (; i + 4 <= e; i += 4) {                                          \
            int2 e0 = EPREAD(i), e1 = EPREAD(i + 1);                          \
            int2 e2 = EPREAD(i + 2), e3 = EPREAD(i + 3);                      \
            uint2 x0 = xp[e0.x * 16 + hl];                                    \
            uint2 x1 = xp[e1.x * 16 + hl];                                    \
            uint2 x2 = xp[e2.x * 16 + hl];                                    \
            uint2 x3 = xp[e3.x * 16 + hl];                                    \
            float v0 = __int_as_float(e0.y), v1 = __int_as_float(e1.y);       \
            float v2 = __int_as_float(e2.y), v3 = __int_as_float(e3.y);       \
            a0 = fmaf(v0, bflo(x0.x), a0); a1 = fmaf(v0, bfhi(x0.x), a1);     \
            a2 = fmaf(v0, bflo(x0.y), a2); a3 = fmaf(v0, bfhi(x0.y), a3);     \
            a0 = fmaf(v1, bflo(x1.x), a0); a1 = fmaf(v1, bfhi(x1.x), a1);     \
            a2 = fmaf(v1, bflo(x1.y), a2); a3 = fmaf(v1, bfhi(x1.y), a3);     \
            a0 = fmaf(v2, bflo(x2.x), a0); a1 = fmaf(v2, bfhi(x2.x), a1);     \
            a2 = fmaf(v2, bflo(x2.y), a2); a3 = fmaf(v2, bfhi(x2.y), a3);     \
            a0 = fmaf(v3, bflo(x3.x), a0); a1 = fmaf(v3, bfhi(x3.x), a1);     \
            a2 = fmaf(v3, bflo(x3.y), a2); a3 = fmaf(v3, bfhi(x3.y), a3);     \
        }                                                                     \
        for (; i < e; ++i) {                                                  \
            int2 e0 = EPREAD(i);                                              \
            uint2 x0 = xp[e0.x * 16 + hl];                                    \
            float v0 = __int_as_float(e0.y);                                  \
            a0 = fmaf(v0, bflo(x0.x), a0); a1 = fmaf(v0, bfhi(x0.x), a1);     \
            a2 = fmaf(v0, bflo(x0.y), a2); a3 = fmaf(v0, bfhi(x0.y), a3);     \
        }                                                                     \
        if (RELU) {                                                           \
            a0 = fmaxf(a0, 0.f); a1 = fmaxf(a1, 0.f);                         \
            a2 = fmaxf(a2, 0.f); a3 = fmaxf(a3, 0.f);                         \
        }                                                                     \
        float4 o; o.x = a0; o.y = a1; o.z = a2; o.w = a3;                     \
        ((float4*)y)[w * 16 + hl] = o;                                        \
    }

template <int D, bool RELU>
__global__ void __launch_bounds__(256) spmm_k(const int* __restrict__ rowptr,
                                              const int2* __restrict__ ep,
                                              const ushort* __restrict__ xb,
                                              void* __restrict__ y) {
    constexpr int CAP = 1536;                  // 12 KB LDS; block mean = 256 edges
    __shared__ int2 eb[CAP];
    __shared__ int sh_s0, sh_n;
    int t = threadIdx.x;
    int g = t >> 4, hl = t & 15;
    int rbase = blockIdx.x * 16;
    int w = rbase + g;

    if (t == 0) {
        int s0 = rowptr[rbase];
        int rend = rbase + 16; if (rend > N_NODES) rend = N_NODES;
        sh_s0 = s0;
        sh_n = rowptr[rend] - s0;
    }
    __syncthreads();
    int s0 = sh_s0, n = sh_n;
    bool inlds = (n <= CAP);
    if (inlds) {
        for (int j = t; j < n; j += 256) eb[j] = ep[s0 + j];   // coalesced stage
    }
    __syncthreads();
    if (w >= N_NODES) return;
    int s = rowptr[w], e = rowptr[w + 1];

    if (inlds) {
        s -= s0; e -= s0;
#define EPL(i) eb[i]
        SPMM_BODY(EPL)
#undef EPL
    } else {                                   // overflow fallback (rare)
#define EPG(i) ep[i]
        SPMM_BODY(EPG)
#undef EPG
    }
}

// ---------------- launch ----------------

extern "C" void kernel_launch(void* const* d_in, const int* in_sizes, int n_in,
                              void* d_out, int out_size, void* d_ws, size_t ws_size,
                              hipStream_t stream) {
    const float* x    = (const float*)d_in[0];
    const float* vals = (const float*)d_in[1];
    const float* W1   = (const float*)d_in[2];
    const float* b1   = (const float*)d_in[3];
    const float* W2   = (const float*)d_in[4];
    const float* b2   = (const float*)d_in[5];
    const float* W3   = (const float*)d_in[6];
    const float* b3   = (const float*)d_in[7];
    const int* row    = (const int*)d_in[8];
    const int* col    = (const int*)d_in[9];
    float* out = (float*)d_out;

    char* ws = (char*)d_ws;
    int2*   ep     = (int2*)  (ws + 0);          // 12,800,000
    int*    rowptr = (int*)   (ws + 12800000);   // 400,004
    int*    gcount = (int*)   (ws + 13250000);   // 3,128
    ushort* Wt1    = (ushort*)(ws + 13601024);   // 32,768
    ushort* Wt2    = (ushort*)(ws + 13633792);   // 32,768
    ushort* Wt3    = (ushort*)(ws + 13666560);   // 16,384
    int*    offT   = (int*)   (ws + 13700096);   // (NBK+1)*NBA*4 = 613,872
    ushort* g64    = (ushort*)(ws + 16000000);   // 12,800,000 (layer-3 gemm out)
    ushort* g      = (ushort*)(ws + 41600000);   // 25,600,000
    ushort* sbuf   = (ushort*)(ws + 67200000);   // 25,600,000  (total 92.8MB)

    // tmp aliases g (dead until gemm L1 writes it; build completes first) — the
    // proven round-10 layout (fusion of binA+gemm1 regressed; reverted).
    int2* tmp = (int2*)g;                        // NBA*EPB*8 = 12,845,056 <= 25.6MB

    // 1) weight converts + gcount zeroing
    hipLaunchKernelGGL(wcvt_k, dim3(64), dim3(256), 0, stream,
                       W1, W2, W3, Wt1, Wt2, Wt3, gcount);

    // 2) CSR phase A (halved LDS atomics)
    hipLaunchKernelGGL(binA_k, dim3(NBA), dim3(1024), 0, stream,
                       row, col, vals, tmp, gcount, offT);
    // 3) CSR phase B (computes own bstart)
    hipLaunchKernelGGL(binB_k, dim3(NBK), dim3(256), 0, stream,
                       tmp, offT, gcount, rowptr, ep);

    const int GEMM_GRID = (N_NODES + 63) / 64;     // 1563
    const int SPMM_GRID = (N_NODES + 15) / 16;     // 6250

    // 4-5) layer 1 (gemm reads fp32 x directly, converts in-register)
    hipLaunchKernelGGL((gemm_k<128, true>), dim3(GEMM_GRID), dim3(256), 0, stream, x, Wt1, b1, g);
    hipLaunchKernelGGL((spmm_k<128, true>), dim3(SPMM_GRID), dim3(256), 0, stream,
                       rowptr, ep, g, sbuf);
    // 6-7) layer 2
    hipLaunchKernelGGL((gemm_k<128, false>), dim3(GEMM_GRID), dim3(256), 0, stream, sbuf, Wt2, b2, g);
    hipLaunchKernelGGL((spmm_k<128, true>), dim3(SPMM_GRID), dim3(256), 0, stream,
                       rowptr, ep, g, sbuf);
    // 8-9) layer 3
    hipLaunchKernelGGL((gemm_k<64, false>), dim3(GEMM_GRID), dim3(256), 0, stream, sbuf, Wt3, b3, g64);
    hipLaunchKernelGGL((spmm_k<64, false>), dim3(SPMM_GRID), dim3(256), 0, stream,
                       rowptr, ep, g64, out);
}

// Round 13
// 290.015 us; speedup vs baseline: 1.0207x; 1.0062x over previous
//
#include <hip/hip_runtime.h>

#define N_NODES 100000
#define N_EDGES 1600000

#define NBK 782    // row buckets of 128 rows: ceil(100000/128)
#define EPB 8192   // edges per binA block
#define NBA 196    // binA blocks: 196*8192 = 1,605,632 >= N_EDGES
#define CAPE 4096  // LDS edge-stage capacity in binB (mean bucket = 2047, sigma ~45)

typedef __attribute__((ext_vector_type(8))) short short8;
typedef __attribute__((ext_vector_type(4))) float f32x4;

__device__ __forceinline__ ushort f2bf(float f) {
    uint u = __float_as_uint(f);
    return (ushort)((u + 0x7fff + ((u >> 16) & 1)) >> 16);   // RNE
}
__device__ __forceinline__ float bflo(uint p) { return __uint_as_float(p << 16); }
__device__ __forceinline__ float bfhi(uint p) { return __uint_as_float(p & 0xffff0000u); }

// ---------------- CSR build: two-pass counting sort by 128-row bucket ----------------
// Phase A: single-pass rank trick (one LDS atomic per edge gives histogram AND rank;
// scatter pass is atomic-free). gcount is GONE — binB derives bucket bases from offT.

__global__ void __launch_bounds__(1024) binA_k(const int* __restrict__ row,
                                               const int* __restrict__ col,
                                               const float* __restrict__ vals,
                                               int2* __restrict__ tmp,
                                               int* __restrict__ offT) {
    __shared__ int cnt[NBK];
    __shared__ int exo[NBK];
    __shared__ int wpart[16];
    int t = threadIdx.x;
    int lane = t & 63;
    int base = blockIdx.x * EPB;

    // stage 8 edges/thread in registers (row/col/vals each read exactly once)
    int rr[8], cc[8], rk[8];
    float vv[8];
#pragma unroll
    for (int u = 0; u < 8; ++u) {
        int e = base + u * 1024 + t;
        bool ok = (e < N_EDGES);
        rr[u] = ok ? row[e] : -1;
        cc[u] = ok ? col[e] : 0;
        vv[u] = ok ? vals[e] : 0.f;
    }

    if (t < NBK) cnt[t] = 0;
    __syncthreads();
#pragma unroll
    for (int u = 0; u < 8; ++u)
        if (rr[u] >= 0) rk[u] = atomicAdd(&cnt[rr[u] >> 7], 1);   // rank + histogram
    __syncthreads();
    int hv = (t < NBK) ? cnt[t] : 0;

    // wave-shuffle inclusive scan over thread order (cnt is zero past NBK)
    int v = hv;
    for (int off = 1; off < 64; off <<= 1) {
        int u2 = __shfl_up(v, off);
        if (lane >= off) v += u2;
    }
    if (lane == 63) wpart[t >> 6] = v;
    __syncthreads();
    if (t == 0) {
        int acc = 0;
#pragma unroll
        for (int i = 0; i < 16; ++i) { int w = wpart[i]; wpart[i] = acc; acc += w; }
    }
    __syncthreads();
    v += wpart[t >> 6];                      // inclusive prefix over cnt[0..t]
    if (t < NBK) {
        int ex = v - hv;
        exo[t] = ex;
        offT[t * NBA + blockIdx.x] = ex;
    }
    if (t == NBK - 1) offT[NBK * NBA + blockIdx.x] = v;  // row NBK = edges in block
    __syncthreads();
    // scatter into block-private region, grouped by bucket — NO atomics
#pragma unroll
    for (int u = 0; u < 8; ++u) {
        if (rr[u] >= 0) {
            int p = exo[rr[u] >> 7] + rk[u];
            int2 w;
            w.x = ((rr[u] & 127) << 17) | cc[u];   // 7-bit row-in-bucket | 17-bit col
            w.y = __float_as_int(vv[u]);
            tmp[base + p] = w;
        }
    }
}

// Phase B body: one block per bucket. bstart[b] = sum_s offT[b][s] (offT[0][s]==0),
// computed from the offT values the block already loads — gcount/bscan eliminated.
// 16-lane group per segment loads coalesced, histograms, packs into ebuf; pass 2
// scatters flat from the packed ebuf to final CSR positions.

__device__ void binB_body(int b, const int2* __restrict__ tmp,
                          const int* __restrict__ offT, int* __restrict__ rowptr,
                          int2* __restrict__ ep) {
    __shared__ int goff[NBA];
    __shared__ int scnt[NBA];
    __shared__ int sdst[NBA];
    __shared__ int h[128];
    __shared__ int cur[128];
    __shared__ int2 ebuf[CAPE];
    __shared__ int wpart[4];
    __shared__ int wq[4];
    __shared__ int hp;
    int t = threadIdx.x;
    int lane = t & 63;

    int o0 = 0, c = 0;
    if (t < NBA) {
        o0 = offT[b * NBA + t];
        int o1 = offT[(b + 1) * NBA + t];
        c = o1 - o0;
        goff[t] = t * EPB + o0;
        scnt[t] = c;
    }
    // bstart[b] = sum_s offT[b*NBA+s] (wave reduce of o0; zero past NBA)
    int part = o0;
#pragma unroll
    for (int off = 1; off < 64; off <<= 1) part += __shfl_xor(part, off);
    if (lane == 0) wq[t >> 6] = part;
    if (b == 0 && t == 0) rowptr[N_NODES] = N_EDGES;

    // exclusive scan of segment counts (wave shuffle, 256 threads)
    int v = c;
    for (int off = 1; off < 64; off <<= 1) {
        int u = __shfl_up(v, off);
        if (lane >= off) v += u;
    }
    if (lane == 63) wpart[t >> 6] = v;
    if (t < 128) h[t] = 0;
    __syncthreads();
    if (t == 0) {
        int acc = 0;
#pragma unroll
        for (int i = 0; i < 4; ++i) { int w = wpart[i]; wpart[i] = acc; acc += w; }
    }
    __syncthreads();
    v += wpart[t >> 6];
    if (t < NBA) sdst[t] = v - c;
    __syncthreads();

    // pass 1: 16-lane group per segment: coalesced load, LDS hist, pack into ebuf
    int grp = t >> 4, gl = t & 15;            // 16 groups of 16 lanes
    for (int s = grp; s < NBA; s += 16) {
        int n = scnt[s], go = goff[s], dd = sdst[s];
        for (int i = gl; i < n; i += 16) {
            int2 e = tmp[go + i];
            atomicAdd(&h[e.x >> 17], 1);
            ebuf[dd + i] = e;
        }
    }
    __syncthreads();
    // exclusive scan over 128 bins (2 waves + 1 partial)
    int hv = (t < 128) ? h[t] : 0;
    int sv = hv;
    for (int off = 1; off < 64; off <<= 1) {
        int u = __shfl_up(sv, off);
        if (lane >= off) sv += u;
    }
    if (t == 63) hp = sv;
    __syncthreads();
    int bs = wq[0] + wq[1] + wq[2] + wq[3];
    if (t < 128) {
        int inc = sv + ((t >= 64) ? hp : 0);
        int ex = inc - hv;
        cur[t] = ex;
        int r = (b << 7) + t;
        if (r < N_NODES) rowptr[r] = bs + ex;
    }
    __syncthreads();
    // pass 2: flat scatter from packed ebuf to final CSR positions
    int T = sdst[NBA - 1] + scnt[NBA - 1];
    for (int j = t; j < T; j += 256) {
        int2 e = ebuf[j];
        int p = atomicAdd(&cur[e.x >> 17], 1);
        int2 w;
        w.x = e.x & 0x1ffff;
        w.y = e.y;
        ep[bs + p] = w;
    }
}

// layer-1 GEMM body (fp32 A converted in-register; 64 rows/block, 256 threads —
// identical shape to the standalone gemm_k<128,true>).

__device__ void gemm1_body(int bid, const float* __restrict__ Xf,
                           const ushort* __restrict__ Wt,
                           const float* __restrict__ bias, ushort* __restrict__ Y) {
    int wv = threadIdx.x >> 6;
    int l = threadIdx.x & 63;
    int lg = l >> 4, lm = l & 15;
    int rbase = bid * 64 + wv * 16;

    int arow = rbase + lm;
    if (arow > N_NODES - 1) arow = N_NODES - 1;     // clamp (stores predicated)

    f32x4 acc[8];
#pragma unroll
    for (int n = 0; n < 8; n++) acc[n] = (f32x4){0.f, 0.f, 0.f, 0.f};

#pragma unroll
    for (int kk = 0; kk < 4; ++kk) {
        const float* ap = Xf + (size_t)arow * 128 + kk * 32 + lg * 8;
        float4 u = *(const float4*)ap;
        float4 v = *(const float4*)(ap + 4);
        short8 a = (short8){(short)f2bf(u.x), (short)f2bf(u.y), (short)f2bf(u.z),
                            (short)f2bf(u.w), (short)f2bf(v.x), (short)f2bf(v.y),
                            (short)f2bf(v.z), (short)f2bf(v.w)};
#pragma unroll
        for (int n = 0; n < 8; ++n) {
            short8 b = *(const short8*)(Wt + (size_t)(n * 16 + lm) * 128 + kk * 32 + lg * 8);
            acc[n] = __builtin_amdgcn_mfma_f32_16x16x32_bf16(a, b, acc[n], 0, 0, 0);
        }
    }

    int r0 = rbase + lg * 4;
#pragma unroll
    for (int n = 0; n < 8; ++n) {
        int c = n * 16 + lm;
        float bj = bias[c];
#pragma unroll
        for (int i = 0; i < 4; ++i) {
            int r = r0 + i;
            if (r < N_NODES) Y[(size_t)r * 128 + c] = f2bf(acc[n][i] + bj);
        }
    }
}

// fused 256-thread dispatch: blocks [0,NBK) run binB; [NBK, NBK+1563) run gemm1.
// (round-11's fusion failed from 1024-thread VGPR quantization -> 1 block/CU;
//  uniform 256-thread blocks keep binB at 4 blocks/CU and gemm at 16 waves/CU.)
__global__ void __launch_bounds__(256) fusedB_k(const int2* __restrict__ tmp,
                                                const int* __restrict__ offT,
                                                int* __restrict__ rowptr,
                                                int2* __restrict__ ep,
                                                const float* __restrict__ x,
                                                const ushort* __restrict__ Wt1,
                                                const float* __restrict__ b1,
                                                ushort* __restrict__ g) {
    if (blockIdx.x < NBK)
        binB_body(blockIdx.x, tmp, offT, rowptr, ep);
    else
        gemm1_body(blockIdx.x - NBK, x, Wt1, b1, g);
}

// ---------------- converts ----------------

// transpose-convert all three weight matrices: Wt[n][k] = bf16(W[k][n]).
__global__ void wcvt_k(const float* __restrict__ W1, const float* __restrict__ W2,
                       const float* __restrict__ W3, ushort* __restrict__ Wt1,
                       ushort* __restrict__ Wt2, ushort* __restrict__ Wt3) {
    int i = blockIdx.x * 256 + threadIdx.x;
    if (i < 16384) {
        int n = i >> 7, k = i & 127;
        Wt1[i] = f2bf(W1[k * 128 + n]);
        Wt2[i] = f2bf(W2[k * 128 + n]);
    }
    if (i < 8192) {
        int n = i >> 7, k = i & 127;
        Wt3[i] = f2bf(W3[k * 64 + n]);
    }
}

// ---------------- GEMM (bf16 in): Y[r, 0..DN) = bf16( Xb[r,:] @ Wt^T + bias ) -------

template <int DN>
__global__ void __launch_bounds__(256) gemm_k(const ushort* __restrict__ Xb,
                                              const ushort* __restrict__ Wt,
                                              const float* __restrict__ bias,
                                              ushort* __restrict__ Y) {
    constexpr int NT = DN / 16;
    int wv = threadIdx.x >> 6;
    int l = threadIdx.x & 63;
    int lg = l >> 4, lm = l & 15;
    int rbase = blockIdx.x * 64 + wv * 16;

    int arow = rbase + lm;
    if (arow > N_NODES - 1) arow = N_NODES - 1;     // clamp (stores predicated)

    f32x4 acc[NT];
#pragma unroll
    for (int n = 0; n < NT; n++) acc[n] = (f32x4){0.f, 0.f, 0.f, 0.f};

#pragma unroll
    for (int kk = 0; kk < 4; ++kk) {
        short8 a = *(const short8*)(Xb + (size_t)arow * 128 + kk * 32 + lg * 8);
#pragma unroll
        for (int n = 0; n < NT; ++n) {
            short8 b = *(const short8*)(Wt + (size_t)(n * 16 + lm) * 128 + kk * 32 + lg * 8);
            acc[n] = __builtin_amdgcn_mfma_f32_16x16x32_bf16(a, b, acc[n], 0, 0, 0);
        }
    }

    int r0 = rbase + lg * 4;
#pragma unroll
    for (int n = 0; n < NT; ++n) {
        int c = n * 16 + lm;
        float bj = bias[c];
#pragma unroll
        for (int i = 0; i < 4; ++i) {
            int r = r0 + i;
            if (r < N_NODES) Y[(size_t)r * DN + c] = f2bf(acc[n][i] + bj);
        }
    }
}

// ---------------- SpMM (CSR; one 16-lane group per row; ep staged via LDS) -----------

#define SPMM_BODY(EPREAD)                                                     \
    if (D == 128) {                                                           \
        const uint4* xp = (const uint4*)xb;                                   \
        float a0 = 0.f, a1 = 0.f, a2 = 0.f, a3 = 0.f;                         \
        float a4 = 0.f, a5 = 0.f, a6 = 0.f, a7 = 0.f;                         \
        int i = s;                                                            \
        for (; i + 4 <= e; i += 4) {                                          \
            int2 e0 = EPREAD(i), e1 = EPREAD(i + 1);                          \
            int2 e2 = EPREAD(i + 2), e3 = EPREAD(i + 3);                      \
            uint4 x0 = xp[e0.x * 16 + hl];                                    \
            uint4 x1 = xp[e1.x * 16 + hl];                                    \
            uint4 x2 = xp[e2.x * 16 + hl];                                    \
            uint4 x3 = xp[e3.x * 16 + hl];                                    \
            float v0 = __int_as_float(e0.y), v1 = __int_as_float(e1.y);       \
            float v2 = __int_as_float(e2.y), v3 = __int_as_float(e3.y);       \
            a0 = fmaf(v0, bflo(x0.x), a0); a1 = fmaf(v0, bfhi(x0.x), a1);     \
            a2 = fmaf(v0, bflo(x0.y), a2); a3 = fmaf(v0, bfhi(x0.y), a3);     \
            a4 = fmaf(v0, bflo(x0.z), a4); a5 = fmaf(v0, bfhi(x0.z), a5);     \
            a6 = fmaf(v0, bflo(x0.w), a6); a7 = fmaf(v0, bfhi(x0.w), a7);     \
            a0 = fmaf(v1, bflo(x1.x), a0); a1 = fmaf(v1, bfhi(x1.x), a1);     \
            a2 = fmaf(v1, bflo(x1.y), a2); a3 = fmaf(v1, bfhi(x1.y), a3);     \
            a4 = fmaf(v1, bflo(x1.z), a4); a5 = fmaf(v1, bfhi(x1.z), a5);     \
            a6 = fmaf(v1, bflo(x1.w), a6); a7 = fmaf(v1, bfhi(x1.w), a7);     \
            a0 = fmaf(v2, bflo(x2.x), a0); a1 = fmaf(v2, bfhi(x2.x), a1);     \
            a2 = fmaf(v2, bflo(x2.y), a2); a3 = fmaf(v2, bfhi(x2.y), a3);     \
            a4 = fmaf(v2, bflo(x2.z), a4); a5 = fmaf(v2, bfhi(x2.z), a5);     \
            a6 = fmaf(v2, bflo(x2.w), a6); a7 = fmaf(v2, bfhi(x2.w), a7);     \
            a0 = fmaf(v3, bflo(x3.x), a0); a1 = fmaf(v3, bfhi(x3.x), a1);     \
            a2 = fmaf(v3, bflo(x3.y), a2); a3 = fmaf(v3, bfhi(x3.y), a3);     \
            a4 = fmaf(v3, bflo(x3.z), a4); a5 = fmaf(v3, bfhi(x3.z), a5);     \
            a6 = fmaf(v3, bflo(x3.w), a6); a7 = fmaf(v3, bfhi(x3.w), a7);     \
        }                                                                     \
        for (; i < e; ++i) {                                                  \
            int2 e0 = EPREAD(i);                                              \
            uint4 x0 = xp[e0.x * 16 + hl];                                    \
            float v0 = __int_as_float(e0.y);                                  \
            a0 = fmaf(v0, bflo(x0.x), a0); a1 = fmaf(v0, bfhi(x0.x), a1);     \
            a2 = fmaf(v0, bflo(x0.y), a2); a3 = fmaf(v0, bfhi(x0.y), a3);     \
            a4 = fmaf(v0, bflo(x0.z), a4); a5 = fmaf(v0, bfhi(x0.z), a5);     \
            a6 = fmaf(v0, bflo(x0.w), a6); a7 = fmaf(v0, bfhi(x0.w), a7);     \
        }                                                                     \
        if (RELU) {                                                           \
            a0 = fmaxf(a0, 0.f); a1 = fmaxf(a1, 0.f);                         \
            a2 = fmaxf(a2, 0.f); a3 = fmaxf(a3, 0.f);                         \
            a4 = fmaxf(a4, 0.f); a5 = fmaxf(a5, 0.f);                         \
            a6 = fmaxf(a6, 0.f); a7 = fmaxf(a7, 0.f);                         \
        }                                                                     \
        uint4 o;                                                              \
        o.x = (uint)f2bf(a0) | ((uint)f2bf(a1) << 16);                        \
        o.y = (uint)f2bf(a2) | ((uint)f2bf(a3) << 16);                        \
        o.z = (uint)f2bf(a4) | ((uint)f2bf(a5) << 16);                        \
        o.w = (uint)f2bf(a6) | ((uint)f2bf(a7) << 16);                        \
        ((uint4*)y)[w * 16 + hl] = o;                                         \
    } else {                                                                  \
        const uint2* xp = (const uint2*)xb;                                   \
        float a0 = 0.f, a1 = 0.f, a2 = 0.f, a3 = 0.f;                         \
        int i = s;                                                            \
        for (; i + 4 <= e; i += 4) {                                          \
            int2 e0 = EPREAD(i), e1 = EPREAD(i + 1);                          \
            int2 e2 = EPREAD(i + 2), e3 = EPREAD(i + 3);                      \
            uint2 x0 = xp[e0.x * 16 + hl];                                    \
            uint2 x1 = xp[e1.x * 16 + hl];                                    \
            uint2 x2 = xp[e2.x * 16 + hl];                                    \
            uint2 x3 = xp[e3.x * 16 + hl];                                    \
            float v0 = __int_as_float(e0.y), v1 = __int_as_float(e1.y);       \
            float v2 = __int_as_float(e2.y), v3 = __int_as_float(e3.y);       \
            a0 = fmaf(v0, bflo(x0.x), a0); a1 = fmaf(v0, bfhi(x0.x), a1);     \
            a2 = fmaf(v0, bflo(x0.y), a2); a3 = fmaf(v0, bfhi(x0.y), a3);     \
            a0 = fmaf(v1, bflo(x1.x), a0); a1 = fmaf(v1, bfhi(x1.x), a1);     \
            a2 = fmaf(v1, bflo(x1.y), a2); a3 = fmaf(v1, bfhi(x1.y), a3);     \
            a0 = fmaf(v2, bflo(x2.x), a0); a1 = fmaf(v2, bfhi(x2.x), a1);     \
            a2 = fmaf(v2, bflo(x2.y), a2); a3 = fmaf(v2, bfhi(x2.y), a3);     \
            a0 = fmaf(v3, bflo(x3.x), a0); a1 = fmaf(v3, bfhi(x3.x), a1);     \
            a2 = fmaf(v3, bflo(x3.y), a2); a3 = fmaf(v3, bfhi(x3.y), a3);     \
        }                                                                     \
        for (; i < e; ++i) {                                                  \
            int2 e0 = EPREAD(i);                                              \
            uint2 x0 = xp[e0.x * 16 + hl];                                    \
            float v0 = __int_as_float(e0.y);                                  \
            a0 = fmaf(v0, bflo(x0.x), a0); a1 = fmaf(v0, bfhi(x0.x), a1);     \
            a2 = fmaf(v0, bflo(x0.y), a2); a3 = fmaf(v0, bfhi(x0.y), a3);     \
        }                                                                     \
        if (RELU) {                                                           \
            a0 = fmaxf(a0, 0.f); a1 = fmaxf(a1, 0.f);                         \
            a2 = fmaxf(a2, 0.f); a3 = fmaxf(a3, 0.f);                         \
        }                                                                     \
        float4 o; o.x = a0; o.y = a1; o.z = a2; o.w = a3;                     \
        ((float4*)y)[w * 16 + hl] = o;                                        \
    }

template <int D, bool RELU>
__global__ void __launch_bounds__(256) spmm_k(const int* __restrict__ rowptr,
                                              const int2* __restrict__ ep,
                                              const ushort* __restrict__ xb,
                                              void* __restrict__ y) {
    constexpr int CAP = 1536;                  // 12 KB LDS; block mean = 256 edges
    __shared__ int2 eb[CAP];
    __shared__ int sh_s0, sh_n;
    int t = threadIdx.x;
    int g = t >> 4, hl = t & 15;
    int rbase = blockIdx.x * 16;
    int w = rbase + g;

    if (t == 0) {
        int s0 = rowptr[rbase];
        int rend = rbase + 16; if (rend > N_NODES) rend = N_NODES;
        sh_s0 = s0;
        sh_n = rowptr[rend] - s0;
    }
    __syncthreads();
    int s0 = sh_s0, n = sh_n;
    bool inlds = (n <= CAP);
    if (inlds) {
        for (int j = t; j < n; j += 256) eb[j] = ep[s0 + j];   // coalesced stage
    }
    __syncthreads();
    if (w >= N_NODES) return;
    int s = rowptr[w], e = rowptr[w + 1];

    if (inlds) {
        s -= s0; e -= s0;
#define EPL(i) eb[i]
        SPMM_BODY(EPL)
#undef EPL
    } else {                                   // overflow fallback (rare)
#define EPG(i) ep[i]
        SPMM_BODY(EPG)
#undef EPG
    }
}

// ---------------- launch ----------------

extern "C" void kernel_launch(void* const* d_in, const int* in_sizes, int n_in,
                              void* d_out, int out_size, void* d_ws, size_t ws_size,
                              hipStream_t stream) {
    const float* x    = (const float*)d_in[0];
    const float* vals = (const float*)d_in[1];
    const float* W1   = (const float*)d_in[2];
    const float* b1   = (const float*)d_in[3];
    const float* W2   = (const float*)d_in[4];
    const float* b2   = (const float*)d_in[5];
    const float* W3   = (const float*)d_in[6];
    const float* b3   = (const float*)d_in[7];
    const int* row    = (const int*)d_in[8];
    const int* col    = (const int*)d_in[9];
    float* out = (float*)d_out;

    char* ws = (char*)d_ws;
    int2*   ep     = (int2*)  (ws + 0);          // 12,800,000
    int*    rowptr = (int*)   (ws + 12800000);   // 400,004
    ushort* Wt1    = (ushort*)(ws + 13601024);   // 32,768
    ushort* Wt2    = (ushort*)(ws + 13633792);   // 32,768
    ushort* Wt3    = (ushort*)(ws + 13666560);   // 16,384
    int*    offT   = (int*)   (ws + 13700096);   // (NBK+1)*NBA*4 = 613,872
    ushort* g64    = (ushort*)(ws + 16000000);   // 12,800,000 (layer-3 gemm out)
    ushort* g      = (ushort*)(ws + 41600000);   // 25,600,000 (gemm out)
    ushort* sbuf   = (ushort*)(ws + 67200000);   // 25,600,000  (total 92.8MB)

    // tmp aliases sbuf (dead until spmm L1 writes it; binB in fusedB completes
    // before then). This keeps binA/binB independent of g so the layer-1 GEMM can
    // run concurrently with binB inside fusedB_k.
    int2* tmp = (int2*)sbuf;                     // NBA*EPB*8 = 12,845,056 <= 25.6MB

    // 1) weight converts
    hipLaunchKernelGGL(wcvt_k, dim3(64), dim3(256), 0, stream,
                       W1, W2, W3, Wt1, Wt2, Wt3);

    // 2) CSR phase A (rank-trick, no gcount)
    hipLaunchKernelGGL(binA_k, dim3(NBA), dim3(1024), 0, stream,
                       row, col, vals, tmp, offT);

    const int GEMM_GRID = (N_NODES + 63) / 64;     // 1563
    const int SPMM_GRID = (N_NODES + 15) / 16;     // 6250

    // 3) fused: CSR phase B (blocks 0..781) + layer-1 GEMM (blocks 782..2344)
    hipLaunchKernelGGL(fusedB_k, dim3(NBK + GEMM_GRID), dim3(256), 0, stream,
                       tmp, offT, rowptr, ep, x, Wt1, b1, g);

    // 4) spmm L1 (overwrites sbuf/tmp — build is complete)
    hipLaunchKernelGGL((spmm_k<128, true>), dim3(SPMM_GRID), dim3(256), 0, stream,
                       rowptr, ep, g, sbuf);
    // 5-6) layer 2
    hipLaunchKernelGGL((gemm_k<128>), dim3(GEMM_GRID), dim3(256), 0, stream, sbuf, Wt2, b2, g);
    hipLaunchKernelGGL((spmm_k<128, true>), dim3(SPMM_GRID), dim3(256), 0, stream,
                       rowptr, ep, g, sbuf);
    // 7-8) layer 3
    hipLaunchKernelGGL((gemm_k<64>), dim3(GEMM_GRID), dim3(256), 0, stream, sbuf, Wt3, b3, g64);
    hipLaunchKernelGGL((spmm_k<64, false>), dim3(SPMM_GRID), dim3(256), 0, stream,
                       rowptr, ep, g64, out);
}

// Round 14
// 244.324 us; speedup vs baseline: 1.2115x; 1.1870x over previous
//
#include <hip/hip_runtime.h>

#define N_NODES 100000
#define N_EDGES 1600000

#define NBK 782    // row buckets of 128 rows: ceil(100000/128)
#define EPB 8192   // edges per binA block
#define NBA 196    // binA blocks: 196*8192 = 1,605,632 >= N_EDGES
#define CAPE 4096  // LDS edge-stage capacity in binB (mean bucket = 2047, sigma ~45)

typedef __attribute__((ext_vector_type(8))) short short8;
typedef __attribute__((ext_vector_type(4))) float f32x4;

__device__ __forceinline__ ushort f2bf(float f) {
    uint u = __float_as_uint(f);
    return (ushort)((u + 0x7fff + ((u >> 16) & 1)) >> 16);   // RNE
}
__device__ __forceinline__ float bflo(uint p) { return __uint_as_float(p << 16); }
__device__ __forceinline__ float bfhi(uint p) { return __uint_as_float(p & 0xffff0000u); }

// ---------------- CSR build: two-pass counting sort by 128-row bucket ----------------
// Phase A: single-pass rank trick (one LDS atomic per edge gives histogram AND rank;
// scatter pass is atomic-free). binB derives bucket bases from offT row-sums.

__global__ void __launch_bounds__(1024) binA_k(const int* __restrict__ row,
                                               const int* __restrict__ col,
                                               const float* __restrict__ vals,
                                               int2* __restrict__ tmp,
                                               int* __restrict__ offT) {
    __shared__ int cnt[NBK];
    __shared__ int exo[NBK];
    __shared__ int wpart[16];
    int t = threadIdx.x;
    int lane = t & 63;
    int base = blockIdx.x * EPB;

    // stage 8 edges/thread in registers (row/col/vals each read exactly once)
    int rr[8], cc[8], rk[8];
    float vv[8];
#pragma unroll
    for (int u = 0; u < 8; ++u) {
        int e = base + u * 1024 + t;
        bool ok = (e < N_EDGES);
        rr[u] = ok ? row[e] : -1;
        cc[u] = ok ? col[e] : 0;
        vv[u] = ok ? vals[e] : 0.f;
    }

    if (t < NBK) cnt[t] = 0;
    __syncthreads();
#pragma unroll
    for (int u = 0; u < 8; ++u)
        if (rr[u] >= 0) rk[u] = atomicAdd(&cnt[rr[u] >> 7], 1);   // rank + histogram
    __syncthreads();
    int hv = (t < NBK) ? cnt[t] : 0;

    // wave-shuffle inclusive scan over thread order (cnt is zero past NBK)
    int v = hv;
    for (int off = 1; off < 64; off <<= 1) {
        int u2 = __shfl_up(v, off);
        if (lane >= off) v += u2;
    }
    if (lane == 63) wpart[t >> 6] = v;
    __syncthreads();
    if (t == 0) {
        int acc = 0;
#pragma unroll
        for (int i = 0; i < 16; ++i) { int w = wpart[i]; wpart[i] = acc; acc += w; }
    }
    __syncthreads();
    v += wpart[t >> 6];                      // inclusive prefix over cnt[0..t]
    if (t < NBK) {
        int ex = v - hv;
        exo[t] = ex;
        offT[t * NBA + blockIdx.x] = ex;
    }
    if (t == NBK - 1) offT[NBK * NBA + blockIdx.x] = v;  // row NBK = edges in block
    __syncthreads();
    // scatter into block-private region, grouped by bucket — NO atomics
#pragma unroll
    for (int u = 0; u < 8; ++u) {
        if (rr[u] >= 0) {
            int p = exo[rr[u] >> 7] + rk[u];
            int2 w;
            w.x = ((rr[u] & 127) << 17) | cc[u];   // 7-bit row-in-bucket | 17-bit col
            w.y = __float_as_int(vv[u]);
            tmp[base + p] = w;
        }
    }
}

// Phase B body: one block per bucket. bstart[b] = sum_s offT[b][s] (offT[0][s]==0).
// 16-lane group per segment loads coalesced, histograms, packs into ebuf; pass 2
// scatters flat from the packed ebuf to final CSR positions.

__device__ void binB_body(int b, const int2* __restrict__ tmp,
                          const int* __restrict__ offT, int* __restrict__ rowptr,
                          int2* __restrict__ ep) {
    __shared__ int goff[NBA];
    __shared__ int scnt[NBA];
    __shared__ int sdst[NBA];
    __shared__ int h[128];
    __shared__ int cur[128];
    __shared__ int2 ebuf[CAPE];
    __shared__ int wpart[4];
    __shared__ int wq[4];
    __shared__ int hp;
    int t = threadIdx.x;
    int lane = t & 63;

    int o0 = 0, c = 0;
    if (t < NBA) {
        o0 = offT[b * NBA + t];
        int o1 = offT[(b + 1) * NBA + t];
        c = o1 - o0;
        goff[t] = t * EPB + o0;
        scnt[t] = c;
    }
    // bstart[b] = sum_s offT[b*NBA+s] (wave reduce of o0; zero past NBA)
    int part = o0;
#pragma unroll
    for (int off = 1; off < 64; off <<= 1) part += __shfl_xor(part, off);
    if (lane == 0) wq[t >> 6] = part;
    if (b == 0 && t == 0) rowptr[N_NODES] = N_EDGES;

    // exclusive scan of segment counts (wave shuffle, 256 threads)
    int v = c;
    for (int off = 1; off < 64; off <<= 1) {
        int u = __shfl_up(v, off);
        if (lane >= off) v += u;
    }
    if (lane == 63) wpart[t >> 6] = v;
    if (t < 128) h[t] = 0;
    __syncthreads();
    if (t == 0) {
        int acc = 0;
#pragma unroll
        for (int i = 0; i < 4; ++i) { int w = wpart[i]; wpart[i] = acc; acc += w; }
    }
    __syncthreads();
    v += wpart[t >> 6];
    if (t < NBA) sdst[t] = v - c;
    __syncthreads();

    // pass 1: 16-lane group per segment: coalesced load, LDS hist, pack into ebuf
    int grp = t >> 4, gl = t & 15;            // 16 groups of 16 lanes
    for (int s = grp; s < NBA; s += 16) {
        int n = scnt[s], go = goff[s], dd = sdst[s];
        for (int i = gl; i < n; i += 16) {
            int2 e = tmp[go + i];
            atomicAdd(&h[e.x >> 17], 1);
            ebuf[dd + i] = e;
        }
    }
    __syncthreads();
    // exclusive scan over 128 bins (2 waves + 1 partial)
    int hv = (t < 128) ? h[t] : 0;
    int sv = hv;
    for (int off = 1; off < 64; off <<= 1) {
        int u = __shfl_up(sv, off);
        if (lane >= off) sv += u;
    }
    if (t == 63) hp = sv;
    __syncthreads();
    int bs = wq[0] + wq[1] + wq[2] + wq[3];
    if (t < 128) {
        int inc = sv + ((t >= 64) ? hp : 0);
        int ex = inc - hv;
        cur[t] = ex;
        int r = (b << 7) + t;
        if (r < N_NODES) rowptr[r] = bs + ex;
    }
    __syncthreads();
    // pass 2: flat scatter from packed ebuf to final CSR positions
    int T = sdst[NBA - 1] + scnt[NBA - 1];
    for (int j = t; j < T; j += 256) {
        int2 e = ebuf[j];
        int p = atomicAdd(&cur[e.x >> 17], 1);
        int2 w;
        w.x = e.x & 0x1ffff;
        w.y = e.y;
        ep[bs + p] = w;
    }
}

// layer-1 GEMM body (fp32 A converted in-register; 64 rows/block, 256 threads).

__device__ void gemm1_body(int bid, const float* __restrict__ Xf,
                           const ushort* __restrict__ Wt,
                           const float* __restrict__ bias, ushort* __restrict__ Y) {
    int wv = threadIdx.x >> 6;
    int l = threadIdx.x & 63;
    int lg = l >> 4, lm = l & 15;
    int rbase = bid * 64 + wv * 16;

    int arow = rbase + lm;
    if (arow > N_NODES - 1) arow = N_NODES - 1;     // clamp (stores predicated)

    f32x4 acc[8];
#pragma unroll
    for (int n = 0; n < 8; n++) acc[n] = (f32x4){0.f, 0.f, 0.f, 0.f};

#pragma unroll
    for (int kk = 0; kk < 4; ++kk) {
        const float* ap = Xf + (size_t)arow * 128 + kk * 32 + lg * 8;
        float4 u = *(const float4*)ap;
        float4 v = *(const float4*)(ap + 4);
        short8 a = (short8){(short)f2bf(u.x), (short)f2bf(u.y), (short)f2bf(u.z),
                            (short)f2bf(u.w), (short)f2bf(v.x), (short)f2bf(v.y),
                            (short)f2bf(v.z), (short)f2bf(v.w)};
#pragma unroll
        for (int n = 0; n < 8; ++n) {
            short8 b = *(const short8*)(Wt + (size_t)(n * 16 + lm) * 128 + kk * 32 + lg * 8);
            acc[n] = __builtin_amdgcn_mfma_f32_16x16x32_bf16(a, b, acc[n], 0, 0, 0);
        }
    }

    int r0 = rbase + lg * 4;
#pragma unroll
    for (int n = 0; n < 8; ++n) {
        int c = n * 16 + lm;
        float bj = bias[c];
#pragma unroll
        for (int i = 0; i < 4; ++i) {
            int r = r0 + i;
            if (r < N_NODES) Y[(size_t)r * 128 + c] = f2bf(acc[n][i] + bj);
        }
    }
}

// fused 256-thread dispatch: blocks [0,NBK) run binB; [NBK, NBK+1563) run gemm1.
__global__ void __launch_bounds__(256) fusedB_k(const int2* __restrict__ tmp,
                                                const int* __restrict__ offT,
                                                int* __restrict__ rowptr,
                                                int2* __restrict__ ep,
                                                const float* __restrict__ x,
                                                const ushort* __restrict__ Wt1,
                                                const float* __restrict__ b1,
                                                ushort* __restrict__ g) {
    if (blockIdx.x < NBK)
        binB_body(blockIdx.x, tmp, offT, rowptr, ep);
    else
        gemm1_body(blockIdx.x - NBK, x, Wt1, b1, g);
}

// ---------------- converts ----------------

// transpose-convert all three weight matrices: Wt[n][k] = bf16(W[k][n]).
__global__ void wcvt_k(const float* __restrict__ W1, const float* __restrict__ W2,
                       const float* __restrict__ W3, ushort* __restrict__ Wt1,
                       ushort* __restrict__ Wt2, ushort* __restrict__ Wt3) {
    int i = blockIdx.x * 256 + threadIdx.x;
    if (i < 16384) {
        int n = i >> 7, k = i & 127;
        Wt1[i] = f2bf(W1[k * 128 + n]);
        Wt2[i] = f2bf(W2[k * 128 + n]);
    }
    if (i < 8192) {
        int n = i >> 7, k = i & 127;
        Wt3[i] = f2bf(W3[k * 64 + n]);
    }
}

// ---------------- SpMM+GEMM fused (layers 1-2 and 2-3) -------------------------------
// Phase 1: spmm over D=128 + RELU (16-lane group per row, ep staged via LDS); result
// goes to a padded LDS tile (16 rows x 128 bf16, pitch 136) instead of HBM.
// Phase 2: the block's 4 waves run the standard MFMA GEMM on that tile:
// Y[r, 0..DNO) = bf16( tile[r,:] @ Wt^T + bias ). Saves the 25.6MB intermediate
// round-trip and the separate GEMM dispatch. DNO = 128 (W2) or 64 (W3).

#define SPMMG_P1(EPREAD)                                                      \
    {                                                                         \
        const uint4* xp = (const uint4*)xb;                                   \
        float a0 = 0.f, a1 = 0.f, a2 = 0.f, a3 = 0.f;                         \
        float a4 = 0.f, a5 = 0.f, a6 = 0.f, a7 = 0.f;                         \
        int i = s;                                                            \
        for (; i + 4 <= e; i += 4) {                                          \
            int2 e0 = EPREAD(i), e1 = EPREAD(i + 1);                          \
            int2 e2 = EPREAD(i + 2), e3 = EPREAD(i + 3);                      \
            uint4 x0 = xp[e0.x * 16 + hl];                                    \
            uint4 x1 = xp[e1.x * 16 + hl];                                    \
            uint4 x2 = xp[e2.x * 16 + hl];                                    \
            uint4 x3 = xp[e3.x * 16 + hl];                                    \
            float v0 = __int_as_float(e0.y), v1 = __int_as_float(e1.y);       \
            float v2 = __int_as_float(e2.y), v3 = __int_as_float(e3.y);       \
            a0 = fmaf(v0, bflo(x0.x), a0); a1 = fmaf(v0, bfhi(x0.x), a1);     \
            a2 = fmaf(v0, bflo(x0.y), a2); a3 = fmaf(v0, bfhi(x0.y), a3);     \
            a4 = fmaf(v0, bflo(x0.z), a4); a5 = fmaf(v0, bfhi(x0.z), a5);     \
            a6 = fmaf(v0, bflo(x0.w), a6); a7 = fmaf(v0, bfhi(x0.w), a7);     \
            a0 = fmaf(v1, bflo(x1.x), a0); a1 = fmaf(v1, bfhi(x1.x), a1);     \
            a2 = fmaf(v1, bflo(x1.y), a2); a3 = fmaf(v1, bfhi(x1.y), a3);     \
            a4 = fmaf(v1, bflo(x1.z), a4); a5 = fmaf(v1, bfhi(x1.z), a5);     \
            a6 = fmaf(v1, bflo(x1.w), a6); a7 = fmaf(v1, bfhi(x1.w), a7);     \
            a0 = fmaf(v2, bflo(x2.x), a0); a1 = fmaf(v2, bfhi(x2.x), a1);     \
            a2 = fmaf(v2, bflo(x2.y), a2); a3 = fmaf(v2, bfhi(x2.y), a3);     \
            a4 = fmaf(v2, bflo(x2.z), a4); a5 = fmaf(v2, bfhi(x2.z), a5);     \
            a6 = fmaf(v2, bflo(x2.w), a6); a7 = fmaf(v2, bfhi(x2.w), a7);     \
            a0 = fmaf(v3, bflo(x3.x), a0); a1 = fmaf(v3, bfhi(x3.x), a1);     \
            a2 = fmaf(v3, bflo(x3.y), a2); a3 = fmaf(v3, bfhi(x3.y), a3);     \
            a4 = fmaf(v3, bflo(x3.z), a4); a5 = fmaf(v3, bfhi(x3.z), a5);     \
            a6 = fmaf(v3, bflo(x3.w), a6); a7 = fmaf(v3, bfhi(x3.w), a7);     \
        }                                                                     \
        for (; i < e; ++i) {                                                  \
            int2 e0 = EPREAD(i);                                              \
            uint4 x0 = xp[e0.x * 16 + hl];                                    \
            float v0 = __int_as_float(e0.y);                                  \
            a0 = fmaf(v0, bflo(x0.x), a0); a1 = fmaf(v0, bfhi(x0.x), a1);     \
            a2 = fmaf(v0, bflo(x0.y), a2); a3 = fmaf(v0, bfhi(x0.y), a3);     \
            a4 = fmaf(v0, bflo(x0.z), a4); a5 = fmaf(v0, bfhi(x0.z), a5);     \
            a6 = fmaf(v0, bflo(x0.w), a6); a7 = fmaf(v0, bfhi(x0.w), a7);     \
        }                                                                     \
        a0 = fmaxf(a0, 0.f); a1 = fmaxf(a1, 0.f);                             \
        a2 = fmaxf(a2, 0.f); a3 = fmaxf(a3, 0.f);                             \
        a4 = fmaxf(a4, 0.f); a5 = fmaxf(a5, 0.f);                             \
        a6 = fmaxf(a6, 0.f); a7 = fmaxf(a7, 0.f);                             \
        uint4 o;                                                              \
        o.x = (uint)f2bf(a0) | ((uint)f2bf(a1) << 16);                        \
        o.y = (uint)f2bf(a2) | ((uint)f2bf(a3) << 16);                        \
        o.z = (uint)f2bf(a4) | ((uint)f2bf(a5) << 16);                        \
        o.w = (uint)f2bf(a6) | ((uint)f2bf(a7) << 16);                        \
        xl4[g * 17 + hl] = o;                                                 \
    }

template <int DNO>
__global__ void __launch_bounds__(256) spmmg_k(const int* __restrict__ rowptr,
                                               const int2* __restrict__ ep,
                                               const ushort* __restrict__ xb,
                                               const ushort* __restrict__ Wt,
                                               const float* __restrict__ bias,
                                               ushort* __restrict__ Y) {
    constexpr int CAP = 1536;                  // 12 KB LDS; block mean = 256 edges
    __shared__ int2 eb[CAP];
    __shared__ uint4 xl4[16 * 17];             // 16 rows x 128 bf16, pitch 136 (4.35KB)
    __shared__ int sh_s0, sh_n;
    int t = threadIdx.x;
    int g = t >> 4, hl = t & 15;
    int rbase = blockIdx.x * 16;               // 6250*16 == N_NODES exactly

    if (t == 0) {
        int s0 = rowptr[rbase];
        sh_s0 = s0;
        sh_n = rowptr[rbase + 16] - s0;
    }
    __syncthreads();
    int s0 = sh_s0, n = sh_n;
    bool inlds = (n <= CAP);
    if (inlds) {
        for (int j = t; j < n; j += 256) eb[j] = ep[s0 + j];   // coalesced stage
    }
    __syncthreads();
    int s = rowptr[rbase + g], e = rowptr[rbase + g + 1];

    if (inlds) {
        s -= s0; e -= s0;
#define EPL(i) eb[i]
        SPMMG_P1(EPL)
#undef EPL
    } else {                                   // overflow fallback (rare)
#define EPG(i) ep[i]
        SPMMG_P1(EPG)
#undef EPG
    }
    __syncthreads();

    // Phase 2: GEMM epilogue on the LDS tile (proven gemm_k fragment mapping)
    constexpr int TPW = DNO / 64;              // col-tiles per wave (2 or 1)
    const ushort* xl = (const ushort*)xl4;
    int wv = t >> 6;
    int l = t & 63;
    int lg = l >> 4, lm = l & 15;
#pragma unroll
    for (int tt = 0; tt < TPW; ++tt) {
        int ct = wv * TPW + tt;
        f32x4 acc = (f32x4){0.f, 0.f, 0.f, 0.f};
#pragma unroll
        for (int kk = 0; kk < 4; ++kk) {
            short8 a = *(const short8*)(xl + lm * 136 + kk * 32 + lg * 8);
            short8 b = *(const short8*)(Wt + (size_t)(ct * 16 + lm) * 128 + kk * 32 + lg * 8);
            acc = __builtin_amdgcn_mfma_f32_16x16x32_bf16(a, b, acc, 0, 0, 0);
        }
        int c = ct * 16 + lm;
        float bj = bias[c];
        int r0 = rbase + lg * 4;
#pragma unroll
        for (int i = 0; i < 4; ++i) {
            int r = r0 + i;
            if (r < N_NODES) Y[(size_t)r * DNO + c] = f2bf(acc[i] + bj);
        }
    }
}

// ---------------- SpMM final (D=64 in, fp32 out, no relu) ----------------------------

__global__ void __launch_bounds__(256) spmm64_k(const int* __restrict__ rowptr,
                                                const int2* __restrict__ ep,
                                                const ushort* __restrict__ xb,
                                                float* __restrict__ y) {
    constexpr int CAP = 1536;
    __shared__ int2 eb[CAP];
    __shared__ int sh_s0, sh_n;
    int t = threadIdx.x;
    int g = t >> 4, hl = t & 15;
    int rbase = blockIdx.x * 16;
    int w = rbase + g;

    if (t == 0) {
        int s0 = rowptr[rbase];
        sh_s0 = s0;
        sh_n = rowptr[rbase + 16] - s0;
    }
    __syncthreads();
    int s0 = sh_s0, n = sh_n;
    bool inlds = (n <= CAP);
    if (inlds) {
        for (int j = t; j < n; j += 256) eb[j] = ep[s0 + j];
    }
    __syncthreads();
    int s = rowptr[w], e = rowptr[w + 1];

    const uint2* xp = (const uint2*)xb;        // row stride 16 uint2
    float a0 = 0.f, a1 = 0.f, a2 = 0.f, a3 = 0.f;

#define S64_BODY(EPREAD)                                                      \
    {                                                                         \
        int i = s;                                                            \
        for (; i + 4 <= e; i += 4) {                                          \
            int2 e0 = EPREAD(i), e1 = EPREAD(i + 1);                          \
            int2 e2 = EPREAD(i + 2), e3 = EPREAD(i + 3);                      \
            uint2 x0 = xp[e0.x * 16 + hl];                                    \
            uint2 x1 = xp[e1.x * 16 + hl];                                    \
            uint2 x2 = xp[e2.x * 16 + hl];                                    \
            uint2 x3 = xp[e3.x * 16 + hl];                                    \
            float v0 = __int_as_float(e0.y), v1 = __int_as_float(e1.y);       \
            float v2 = __int_as_float(e2.y), v3 = __int_as_float(e3.y);       \
            a0 = fmaf(v0, bflo(x0.x), a0); a1 = fmaf(v0, bfhi(x0.x), a1);     \
            a2 = fmaf(v0, bflo(x0.y), a2); a3 = fmaf(v0, bfhi(x0.y), a3);     \
            a0 = fmaf(v1, bflo(x1.x), a0); a1 = fmaf(v1, bfhi(x1.x), a1);     \
            a2 = fmaf(v1, bflo(x1.y), a2); a3 = fmaf(v1, bfhi(x1.y), a3);     \
            a0 = fmaf(v2, bflo(x2.x), a0); a1 = fmaf(v2, bfhi(x2.x), a1);     \
            a2 = fmaf(v2, bflo(x2.y), a2); a3 = fmaf(v2, bfhi(x2.y), a3);     \
            a0 = fmaf(v3, bflo(x3.x), a0); a1 = fmaf(v3, bfhi(x3.x), a1);     \
            a2 = fmaf(v3, bflo(x3.y), a2); a3 = fmaf(v3, bfhi(x3.y), a3);     \
        }                                                                     \
        for (; i < e; ++i) {                                                  \
            int2 e0 = EPREAD(i);                                              \
            uint2 x0 = xp[e0.x * 16 + hl];                                    \
            float v0 = __int_as_float(e0.y);                                  \
            a0 = fmaf(v0, bflo(x0.x), a0); a1 = fmaf(v0, bfhi(x0.x), a1);     \
            a2 = fmaf(v0, bflo(x0.y), a2); a3 = fmaf(v0, bfhi(x0.y), a3);     \
        }                                                                     \
    }

    if (inlds) {
        s -= s0; e -= s0;
#define EPL(i) eb[i]
        S64_BODY(EPL)
#undef EPL
    } else {
#define EPG(i) ep[i]
        S64_BODY(EPG)
#undef EPG
    }
#undef S64_BODY
    float4 o; o.x = a0; o.y = a1; o.z = a2; o.w = a3;
    ((float4*)y)[w * 16 + hl] = o;             // final output fp32
}

// ---------------- launch ----------------

extern "C" void kernel_launch(void* const* d_in, const int* in_sizes, int n_in,
                              void* d_out, int out_size, void* d_ws, size_t ws_size,
                              hipStream_t stream) {
    const float* x    = (const float*)d_in[0];
    const float* vals = (const float*)d_in[1];
    const float* W1   = (const float*)d_in[2];
    const float* b1   = (const float*)d_in[3];
    const float* W2   = (const float*)d_in[4];
    const float* b2   = (const float*)d_in[5];
    const float* W3   = (const float*)d_in[6];
    const float* b3   = (const float*)d_in[7];
    const int* row    = (const int*)d_in[8];
    const int* col    = (const int*)d_in[9];
    float* out = (float*)d_out;

    char* ws = (char*)d_ws;
    int2*   ep     = (int2*)  (ws + 0);          // 12,800,000
    int*    rowptr = (int*)   (ws + 12800000);   // 400,004
    ushort* Wt1    = (ushort*)(ws + 13601024);   // 32,768
    ushort* Wt2    = (ushort*)(ws + 13633792);   // 32,768
    ushort* Wt3    = (ushort*)(ws + 13666560);   // 16,384
    int*    offT   = (int*)   (ws + 13700096);   // (NBK+1)*NBA*4 = 613,872
    ushort* g64    = (ushort*)(ws + 16000000);   // 12,800,000 (layer 2-3 fused out)
    ushort* g      = (ushort*)(ws + 41600000);   // 25,600,000 (gemm1 out)
    ushort* sbuf   = (ushort*)(ws + 67200000);   // 25,600,000  (total 92.8MB)

    // tmp aliases sbuf (dead until spmmg1 writes it; binB in fusedB completes first).
    int2* tmp = (int2*)sbuf;                     // NBA*EPB*8 = 12,845,056 <= 25.6MB

    // 1) weight converts
    hipLaunchKernelGGL(wcvt_k, dim3(64), dim3(256), 0, stream,
                       W1, W2, W3, Wt1, Wt2, Wt3);

    // 2) CSR phase A
    hipLaunchKernelGGL(binA_k, dim3(NBA), dim3(1024), 0, stream,
                       row, col, vals, tmp, offT);

    const int GEMM_GRID = (N_NODES + 63) / 64;     // 1563
    const int SPMM_GRID = N_NODES / 16;            // 6250 (exact)

    // 3) fused: CSR phase B (blocks 0..781) + layer-1 GEMM (blocks 782..2344)
    hipLaunchKernelGGL(fusedB_k, dim3(NBK + GEMM_GRID), dim3(256), 0, stream,
                       tmp, offT, rowptr, ep, x, Wt1, b1, g);

    // 4) spmm1 + gemm2 fused (reads g, writes sbuf — tmp dead now)
    hipLaunchKernelGGL((spmmg_k<128>), dim3(SPMM_GRID), dim3(256), 0, stream,
                       rowptr, ep, g, Wt2, b2, sbuf);
    // 5) spmm2 + gemm3 fused
    hipLaunchKernelGGL((spmmg_k<64>), dim3(SPMM_GRID), dim3(256), 0, stream,
                       rowptr, ep, sbuf, Wt3, b3, g64);
    // 6) spmm3 (final, fp32 out)
    hipLaunchKernelGGL(spmm64_k, dim3(SPMM_GRID), dim3(256), 0, stream,
                       rowptr, ep, g64, out);
}

// Round 15
// 239.405 us; speedup vs baseline: 1.2364x; 1.0205x over previous
//
#include <hip/hip_runtime.h>

#define N_NODES 100000
#define N_EDGES 1600000

#define NBK 782    // row buckets of 128 rows: ceil(100000/128)
#define EPB 8192   // edges per binA block
#define NBA 196    // binA blocks: 196*8192 = 1,605,632 >= N_EDGES
#define CAPE 2688  // LDS edge-stage cap in binB (bucket mean 2048, sigma 45 -> 14σ)

typedef __attribute__((ext_vector_type(8))) short short8;
typedef __attribute__((ext_vector_type(4))) float f32x4;

__device__ __forceinline__ ushort f2bf(float f) {
    uint u = __float_as_uint(f);
    return (ushort)((u + 0x7fff + ((u >> 16) & 1)) >> 16);   // RNE
}
__device__ __forceinline__ float bflo(uint p) { return __uint_as_float(p << 16); }
__device__ __forceinline__ float bfhi(uint p) { return __uint_as_float(p & 0xffff0000u); }

// ---------------- CSR build: two-pass counting sort by 128-row bucket ----------------
// Phase A: single-pass rank trick (one LDS atomic per edge gives histogram AND rank;
// scatter pass is atomic-free). binB derives bucket bases from offT row-sums.
// The weight transpose-convert rides along as 16 extra blocks (binA's 196-block grid
// leaves 60 CUs idle — wcvt is free there, and one dispatch+gap is deleted).

__device__ void binA_body(int bid, const int* __restrict__ row,
                          const int* __restrict__ col, const float* __restrict__ vals,
                          int2* __restrict__ tmp, int* __restrict__ offT) {
    __shared__ int cnt[NBK];
    __shared__ int exo[NBK];
    __shared__ int wpart[16];
    int t = threadIdx.x;
    int lane = t & 63;
    int base = bid * EPB;

    // stage 8 edges/thread in registers (row/col/vals each read exactly once)
    int rr[8], cc[8], rk[8];
    float vv[8];
#pragma unroll
    for (int u = 0; u < 8; ++u) {
        int e = base + u * 1024 + t;
        bool ok = (e < N_EDGES);
        rr[u] = ok ? row[e] : -1;
        cc[u] = ok ? col[e] : 0;
        vv[u] = ok ? vals[e] : 0.f;
    }

    if (t < NBK) cnt[t] = 0;
    __syncthreads();
#pragma unroll
    for (int u = 0; u < 8; ++u)
        if (rr[u] >= 0) rk[u] = atomicAdd(&cnt[rr[u] >> 7], 1);   // rank + histogram
    __syncthreads();
    int hv = (t < NBK) ? cnt[t] : 0;

    // wave-shuffle inclusive scan over thread order (cnt is zero past NBK)
    int v = hv;
    for (int off = 1; off < 64; off <<= 1) {
        int u2 = __shfl_up(v, off);
        if (lane >= off) v += u2;
    }
    if (lane == 63) wpart[t >> 6] = v;
    __syncthreads();
    if (t == 0) {
        int acc = 0;
#pragma unroll
        for (int i = 0; i < 16; ++i) { int w = wpart[i]; wpart[i] = acc; acc += w; }
    }
    __syncthreads();
    v += wpart[t >> 6];                      // inclusive prefix over cnt[0..t]
    if (t < NBK) {
        int ex = v - hv;
        exo[t] = ex;
        offT[t * NBA + bid] = ex;
    }
    if (t == NBK - 1) offT[NBK * NBA + bid] = v;  // row NBK = edges in block
    __syncthreads();
    // scatter into block-private region, grouped by bucket — NO atomics
#pragma unroll
    for (int u = 0; u < 8; ++u) {
        if (rr[u] >= 0) {
            int p = exo[rr[u] >> 7] + rk[u];
            int2 w;
            w.x = ((rr[u] & 127) << 17) | cc[u];   // 7-bit row-in-bucket | 17-bit col
            w.y = __float_as_int(vv[u]);
            tmp[base + p] = w;
        }
    }
}

__device__ void wcvt_body(int bid, const float* __restrict__ W1,
                          const float* __restrict__ W2, const float* __restrict__ W3,
                          ushort* __restrict__ Wt1, ushort* __restrict__ Wt2,
                          ushort* __restrict__ Wt3) {
    int i = bid * 1024 + threadIdx.x;        // 16 blocks x 1024 = 16384
    if (i < 16384) {
        int n = i >> 7, k = i & 127;
        Wt1[i] = f2bf(W1[k * 128 + n]);
        Wt2[i] = f2bf(W2[k * 128 + n]);
    }
    if (i < 8192) {
        int n = i >> 7, k = i & 127;
        Wt3[i] = f2bf(W3[k * 64 + n]);
    }
}

__global__ void __launch_bounds__(1024) binA_k(const int* __restrict__ row,
                                               const int* __restrict__ col,
                                               const float* __restrict__ vals,
                                               int2* __restrict__ tmp,
                                               int* __restrict__ offT,
                                               const float* __restrict__ W1,
                                               const float* __restrict__ W2,
                                               const float* __restrict__ W3,
                                               ushort* __restrict__ Wt1,
                                               ushort* __restrict__ Wt2,
                                               ushort* __restrict__ Wt3) {
    if (blockIdx.x < NBA)
        binA_body(blockIdx.x, row, col, vals, tmp, offT);
    else
        wcvt_body(blockIdx.x - NBA, W1, W2, W3, Wt1, Wt2, Wt3);
}

// Phase B body: one block per bucket. bstart[b] = sum_s offT[b][s] (offT[0][s]==0).
// 16-lane group per segment loads coalesced, histograms, packs into ebuf; pass 2
// scatters flat from the packed ebuf to final CSR positions.

__device__ void binB_body(int b, const int2* __restrict__ tmp,
                          const int* __restrict__ offT, int* __restrict__ rowptr,
                          int2* __restrict__ ep) {
    __shared__ int goff[NBA];
    __shared__ int scnt[NBA];
    __shared__ int sdst[NBA];
    __shared__ int h[128];
    __shared__ int cur[128];
    __shared__ int2 ebuf[CAPE];
    __shared__ int wpart[4];
    __shared__ int wq[4];
    __shared__ int hp;
    int t = threadIdx.x;
    int lane = t & 63;

    int o0 = 0, c = 0;
    if (t < NBA) {
        o0 = offT[b * NBA + t];
        int o1 = offT[(b + 1) * NBA + t];
        c = o1 - o0;
        goff[t] = t * EPB + o0;
        scnt[t] = c;
    }
    // bstart[b] = sum_s offT[b*NBA+s] (wave reduce of o0; zero past NBA)
    int part = o0;
#pragma unroll
    for (int off = 1; off < 64; off <<= 1) part += __shfl_xor(part, off);
    if (lane == 0) wq[t >> 6] = part;
    if (b == 0 && t == 0) rowptr[N_NODES] = N_EDGES;

    // exclusive scan of segment counts (wave shuffle, 256 threads)
    int v = c;
    for (int off = 1; off < 64; off <<= 1) {
        int u = __shfl_up(v, off);
        if (lane >= off) v += u;
    }
    if (lane == 63) wpart[t >> 6] = v;
    if (t < 128) h[t] = 0;
    __syncthreads();
    if (t == 0) {
        int acc = 0;
#pragma unroll
        for (int i = 0; i < 4; ++i) { int w = wpart[i]; wpart[i] = acc; acc += w; }
    }
    __syncthreads();
    v += wpart[t >> 6];
    if (t < NBA) sdst[t] = v - c;
    __syncthreads();

    // pass 1: 16-lane group per segment: coalesced load, LDS hist, pack into ebuf
    int grp = t >> 4, gl = t & 15;            // 16 groups of 16 lanes
    for (int s = grp; s < NBA; s += 16) {
        int n = scnt[s], go = goff[s], dd = sdst[s];
        for (int i = gl; i < n; i += 16) {
            int2 e = tmp[go + i];
            atomicAdd(&h[e.x >> 17], 1);
            ebuf[dd + i] = e;
        }
    }
    __syncthreads();
    // exclusive scan over 128 bins (2 waves + 1 partial)
    int hv = (t < 128) ? h[t] : 0;
    int sv = hv;
    for (int off = 1; off < 64; off <<= 1) {
        int u = __shfl_up(sv, off);
        if (lane >= off) sv += u;
    }
    if (t == 63) hp = sv;
    __syncthreads();
    int bs = wq[0] + wq[1] + wq[2] + wq[3];
    if (t < 128) {
        int inc = sv + ((t >= 64) ? hp : 0);
        int ex = inc - hv;
        cur[t] = ex;
        int r = (b << 7) + t;
        if (r < N_NODES) rowptr[r] = bs + ex;
    }
    __syncthreads();
    // pass 2: flat scatter from packed ebuf to final CSR positions
    int T = sdst[NBA - 1] + scnt[NBA - 1];
    for (int j = t; j < T; j += 256) {
        int2 e = ebuf[j];
        int p = atomicAdd(&cur[e.x >> 17], 1);
        int2 w;
        w.x = e.x & 0x1ffff;
        w.y = e.y;
        ep[bs + p] = w;
    }
}

// layer-1 GEMM body (fp32 A converted in-register; 64 rows/block, 256 threads).

__device__ void gemm1_body(int bid, const float* __restrict__ Xf,
                           const ushort* __restrict__ Wt,
                           const float* __restrict__ bias, ushort* __restrict__ Y) {
    int wv = threadIdx.x >> 6;
    int l = threadIdx.x & 63;
    int lg = l >> 4, lm = l & 15;
    int rbase = bid * 64 + wv * 16;

    int arow = rbase + lm;
    if (arow > N_NODES - 1) arow = N_NODES - 1;     // clamp (stores predicated)

    f32x4 acc[8];
#pragma unroll
    for (int n = 0; n < 8; n++) acc[n] = (f32x4){0.f, 0.f, 0.f, 0.f};

#pragma unroll
    for (int kk = 0; kk < 4; ++kk) {
        const float* ap = Xf + (size_t)arow * 128 + kk * 32 + lg * 8;
        float4 u = *(const float4*)ap;
        float4 v = *(const float4*)(ap + 4);
        short8 a = (short8){(short)f2bf(u.x), (short)f2bf(u.y), (short)f2bf(u.z),
                            (short)f2bf(u.w), (short)f2bf(v.x), (short)f2bf(v.y),
                            (short)f2bf(v.z), (short)f2bf(v.w)};
#pragma unroll
        for (int n = 0; n < 8; ++n) {
            short8 b = *(const short8*)(Wt + (size_t)(n * 16 + lm) * 128 + kk * 32 + lg * 8);
            acc[n] = __builtin_amdgcn_mfma_f32_16x16x32_bf16(a, b, acc[n], 0, 0, 0);
        }
    }

    int r0 = rbase + lg * 4;
#pragma unroll
    for (int n = 0; n < 8; ++n) {
        int c = n * 16 + lm;
        float bj = bias[c];
#pragma unroll
        for (int i = 0; i < 4; ++i) {
            int r = r0 + i;
            if (r < N_NODES) Y[(size_t)r * 128 + c] = f2bf(acc[n][i] + bj);
        }
    }
}

// fused 256-thread dispatch: blocks [0,NBK) run binB; [NBK, NBK+1563) run gemm1.
__global__ void __launch_bounds__(256) fusedB_k(const int2* __restrict__ tmp,
                                                const int* __restrict__ offT,
                                                int* __restrict__ rowptr,
                                                int2* __restrict__ ep,
                                                const float* __restrict__ x,
                                                const ushort* __restrict__ Wt1,
                                                const float* __restrict__ b1,
                                                ushort* __restrict__ g) {
    if (blockIdx.x < NBK)
        binB_body(blockIdx.x, tmp, offT, rowptr, ep);
    else
        gemm1_body(blockIdx.x - NBK, x, Wt1, b1, g);
}

// ---------------- SpMM+GEMM fused (layers 1-2 and 2-3) -------------------------------
// Phase 1: spmm over D=128 + RELU (16-lane group per row, ep staged via LDS); result
// goes to a padded LDS tile (16 rows x 128 bf16, pitch 136) instead of HBM.
// Phase 2: the block's 4 waves run the standard MFMA GEMM on that tile:
// Y[r, 0..DNO) = bf16( tile[r,:] @ Wt^T + bias ). Saves the 25.6MB intermediate
// round-trip and the separate GEMM dispatch. DNO = 128 (W2) or 64 (W3).

#define SPMMG_P1(EPREAD)                                                      \
    {                                                                         \
        const uint4* xp = (const uint4*)xb;                                   \
        float a0 = 0.f, a1 = 0.f, a2 = 0.f, a3 = 0.f;                         \
        float a4 = 0.f, a5 = 0.f, a6 = 0.f, a7 = 0.f;                         \
        int i = s;                                                            \
        for (; i + 4 <= e; i += 4) {                                          \
            int2 e0 = EPREAD(i), e1 = EPREAD(i + 1);                          \
            int2 e2 = EPREAD(i + 2), e3 = EPREAD(i + 3);                      \
            uint4 x0 = xp[e0.x * 16 + hl];                                    \
            uint4 x1 = xp[e1.x * 16 + hl];                                    \
            uint4 x2 = xp[e2.x * 16 + hl];                                    \
            uint4 x3 = xp[e3.x * 16 + hl];                                    \
            float v0 = __int_as_float(e0.y), v1 = __int_as_float(e1.y);       \
            float v2 = __int_as_float(e2.y), v3 = __int_as_float(e3.y);       \
            a0 = fmaf(v0, bflo(x0.x), a0); a1 = fmaf(v0, bfhi(x0.x), a1);     \
            a2 = fmaf(v0, bflo(x0.y), a2); a3 = fmaf(v0, bfhi(x0.y), a3);     \
            a4 = fmaf(v0, bflo(x0.z), a4); a5 = fmaf(v0, bfhi(x0.z), a5);     \
            a6 = fmaf(v0, bflo(x0.w), a6); a7 = fmaf(v0, bfhi(x0.w), a7);     \
            a0 = fmaf(v1, bflo(x1.x), a0); a1 = fmaf(v1, bfhi(x1.x), a1);     \
            a2 = fmaf(v1, bflo(x1.y), a2); a3 = fmaf(v1, bfhi(x1.y), a3);     \
            a4 = fmaf(v1, bflo(x1.z), a4); a5 = fmaf(v1, bfhi(x1.z), a5);     \
            a6 = fmaf(v1, bflo(x1.w), a6); a7 = fmaf(v1, bfhi(x1.w), a7);     \
            a0 = fmaf(v2, bflo(x2.x), a0); a1 = fmaf(v2, bfhi(x2.x), a1);     \
            a2 = fmaf(v2, bflo(x2.y), a2); a3 = fmaf(v2, bfhi(x2.y), a3);     \
            a4 = fmaf(v2, bflo(x2.z), a4); a5 = fmaf(v2, bfhi(x2.z), a5);     \
            a6 = fmaf(v2, bflo(x2.w), a6); a7 = fmaf(v2, bfhi(x2.w), a7);     \
            a0 = fmaf(v3, bflo(x3.x), a0); a1 = fmaf(v3, bfhi(x3.x), a1);     \
            a2 = fmaf(v3, bflo(x3.y), a2); a3 = fmaf(v3, bfhi(x3.y), a3);     \
            a4 = fmaf(v3, bflo(x3.z), a4); a5 = fmaf(v3, bfhi(x3.z), a5);     \
            a6 = fmaf(v3, bflo(x3.w), a6); a7 = fmaf(v3, bfhi(x3.w), a7);     \
        }                                                                     \
        for (; i < e; ++i) {                                                  \
            int2 e0 = EPREAD(i);                                              \
            uint4 x0 = xp[e0.x * 16 + hl];                                    \
            float v0 = __int_as_float(e0.y);                                  \
            a0 = fmaf(v0, bflo(x0.x), a0); a1 = fmaf(v0, bfhi(x0.x), a1);     \
            a2 = fmaf(v0, bflo(x0.y), a2); a3 = fmaf(v0, bfhi(x0.y), a3);     \
            a4 = fmaf(v0, bflo(x0.z), a4); a5 = fmaf(v0, bfhi(x0.z), a5);     \
            a6 = fmaf(v0, bflo(x0.w), a6); a7 = fmaf(v0, bfhi(x0.w), a7);     \
        }                                                                     \
        a0 = fmaxf(a0, 0.f); a1 = fmaxf(a1, 0.f);                             \
        a2 = fmaxf(a2, 0.f); a3 = fmaxf(a3, 0.f);                             \
        a4 = fmaxf(a4, 0.f); a5 = fmaxf(a5, 0.f);                             \
        a6 = fmaxf(a6, 0.f); a7 = fmaxf(a7, 0.f);                             \
        uint4 o;                                                              \
        o.x = (uint)f2bf(a0) | ((uint)f2bf(a1) << 16);                        \
        o.y = (uint)f2bf(a2) | ((uint)f2bf(a3) << 16);                        \
        o.z = (uint)f2bf(a4) | ((uint)f2bf(a5) << 16);                        \
        o.w = (uint)f2bf(a6) | ((uint)f2bf(a7) << 16);                        \
        xl4[g * 17 + hl] = o;                                                 \
    }

template <int DNO>
__global__ void __launch_bounds__(256) spmmg_k(const int* __restrict__ rowptr,
                                               const int2* __restrict__ ep,
                                               const ushort* __restrict__ xb,
                                               const ushort* __restrict__ Wt,
                                               const float* __restrict__ bias,
                                               ushort* __restrict__ Y) {
    constexpr int CAP = 1536;                  // 12 KB LDS; block mean = 256 edges
    __shared__ int2 eb[CAP];
    __shared__ uint4 xl4[16 * 17];             // 16 rows x 128 bf16, pitch 136 (4.35KB)
    __shared__ int sh_s0, sh_n;
    int t = threadIdx.x;
    int g = t >> 4, hl = t & 15;
    int rbase = blockIdx.x * 16;               // 6250*16 == N_NODES exactly

    if (t == 0) {
        int s0 = rowptr[rbase];
        sh_s0 = s0;
        sh_n = rowptr[rbase + 16] - s0;
    }
    __syncthreads();
    int s0 = sh_s0, n = sh_n;
    bool inlds = (n <= CAP);
    if (inlds) {
        for (int j = t; j < n; j += 256) eb[j] = ep[s0 + j];   // coalesced stage
    }
    __syncthreads();
    int s = rowptr[rbase + g], e = rowptr[rbase + g + 1];

    if (inlds) {
        s -= s0; e -= s0;
#define EPL(i) eb[i]
        SPMMG_P1(EPL)
#undef EPL
    } else {                                   // overflow fallback (rare)
#define EPG(i) ep[i]
        SPMMG_P1(EPG)
#undef EPG
    }
    __syncthreads();

    // Phase 2: GEMM epilogue on the LDS tile (proven gemm_k fragment mapping)
    constexpr int TPW = DNO / 64;              // col-tiles per wave (2 or 1)
    const ushort* xl = (const ushort*)xl4;
    int wv = t >> 6;
    int l = t & 63;
    int lg = l >> 4, lm = l & 15;
#pragma unroll
    for (int tt = 0; tt < TPW; ++tt) {
        int ct = wv * TPW + tt;
        f32x4 acc = (f32x4){0.f, 0.f, 0.f, 0.f};
#pragma unroll
        for (int kk = 0; kk < 4; ++kk) {
            short8 a = *(const short8*)(xl + lm * 136 + kk * 32 + lg * 8);
            short8 b = *(const short8*)(Wt + (size_t)(ct * 16 + lm) * 128 + kk * 32 + lg * 8);
            acc = __builtin_amdgcn_mfma_f32_16x16x32_bf16(a, b, acc, 0, 0, 0);
        }
        int c = ct * 16 + lm;
        float bj = bias[c];
        int r0 = rbase + lg * 4;
#pragma unroll
        for (int i = 0; i < 4; ++i) {
            int r = r0 + i;
            if (r < N_NODES) Y[(size_t)r * DNO + c] = f2bf(acc[i] + bj);
        }
    }
}

// ---------------- SpMM final (D=64 in, fp32 out, no relu) ----------------------------

__global__ void __launch_bounds__(256) spmm64_k(const int* __restrict__ rowptr,
                                                const int2* __restrict__ ep,
                                                const ushort* __restrict__ xb,
                                                float* __restrict__ y) {
    constexpr int CAP = 1536;
    __shared__ int2 eb[CAP];
    __shared__ int sh_s0, sh_n;
    int t = threadIdx.x;
    int g = t >> 4, hl = t & 15;
    int rbase = blockIdx.x * 16;
    int w = rbase + g;

    if (t == 0) {
        int s0 = rowptr[rbase];
        sh_s0 = s0;
        sh_n = rowptr[rbase + 16] - s0;
    }
    __syncthreads();
    int s0 = sh_s0, n = sh_n;
    bool inlds = (n <= CAP);
    if (inlds) {
        for (int j = t; j < n; j += 256) eb[j] = ep[s0 + j];
    }
    __syncthreads();
    int s = rowptr[w], e = rowptr[w + 1];

    const uint2* xp = (const uint2*)xb;        // row stride 16 uint2
    float a0 = 0.f, a1 = 0.f, a2 = 0.f, a3 = 0.f;

#define S64_BODY(EPREAD)                                                      \
    {                                                                         \
        int i = s;                                                            \
        for (; i + 4 <= e; i += 4) {                                          \
            int2 e0 = EPREAD(i), e1 = EPREAD(i + 1);                          \
            int2 e2 = EPREAD(i + 2), e3 = EPREAD(i + 3);                      \
            uint2 x0 = xp[e0.x * 16 + hl];                                    \
            uint2 x1 = xp[e1.x * 16 + hl];                                    \
            uint2 x2 = xp[e2.x * 16 + hl];                                    \
            uint2 x3 = xp[e3.x * 16 + hl];                                    \
            float v0 = __int_as_float(e0.y), v1 = __int_as_float(e1.y);       \
            float v2 = __int_as_float(e2.y), v3 = __int_as_float(e3.y);       \
            a0 = fmaf(v0, bflo(x0.x), a0); a1 = fmaf(v0, bfhi(x0.x), a1);     \
            a2 = fmaf(v0, bflo(x0.y), a2); a3 = fmaf(v0, bfhi(x0.y), a3);     \
            a0 = fmaf(v1, bflo(x1.x), a0); a1 = fmaf(v1, bfhi(x1.x), a1);     \
            a2 = fmaf(v1, bflo(x1.y), a2); a3 = fmaf(v1, bfhi(x1.y), a3);     \
            a0 = fmaf(v2, bflo(x2.x), a0); a1 = fmaf(v2, bfhi(x2.x), a1);     \
            a2 = fmaf(v2, bflo(x2.y), a2); a3 = fmaf(v2, bfhi(x2.y), a3);     \
            a0 = fmaf(v3, bflo(x3.x), a0); a1 = fmaf(v3, bfhi(x3.x), a1);     \
            a2 = fmaf(v3, bflo(x3.y), a2); a3 = fmaf(v3, bfhi(x3.y), a3);     \
        }                                                                     \
        for (; i < e; ++i) {                                                  \
            int2 e0 = EPREAD(i);                                              \
            uint2 x0 = xp[e0.x * 16 + hl];                                    \
            float v0 = __int_as_float(e0.y);                                  \
            a0 = fmaf(v0, bflo(x0.x), a0); a1 = fmaf(v0, bfhi(x0.x), a1);     \
            a2 = fmaf(v0, bflo(x0.y), a2); a3 = fmaf(v0, bfhi(x0.y), a3);     \
        }                                                                     \
    }

    if (inlds) {
        s -= s0; e -= s0;
#define EPL(i) eb[i]
        S64_BODY(EPL)
#undef EPL
    } else {
#define EPG(i) ep[i]
        S64_BODY(EPG)
#undef EPG
    }
#undef S64_BODY
    float4 o; o.x = a0; o.y = a1; o.z = a2; o.w = a3;
    ((float4*)y)[w * 16 + hl] = o;             // final output fp32
}

// ---------------- launch ----------------

extern "C" void kernel_launch(void* const* d_in, const int* in_sizes, int n_in,
                              void* d_out, int out_size, void* d_ws, size_t ws_size,
                              hipStream_t stream) {
    const float* x    = (const float*)d_in[0];
    const float* vals = (const float*)d_in[1];
    const float* W1   = (const float*)d_in[2];
    const float* b1   = (const float*)d_in[3];
    const float* W2   = (const float*)d_in[4];
    const float* b2   = (const float*)d_in[5];
    const float* W3   = (const float*)d_in[6];
    const float* b3   = (const float*)d_in[7];
    const int* row    = (const int*)d_in[8];
    const int* col    = (const int*)d_in[9];
    float* out = (float*)d_out;

    char* ws = (char*)d_ws;
    int2*   ep     = (int2*)  (ws + 0);          // 12,800,000
    int*    rowptr = (int*)   (ws + 12800000);   // 400,004
    ushort* Wt1    = (ushort*)(ws + 13601024);   // 32,768
    ushort* Wt2    = (ushort*)(ws + 13633792);   // 32,768
    ushort* Wt3    = (ushort*)(ws + 13666560);   // 16,384
    int*    offT   = (int*)   (ws + 13700096);   // (NBK+1)*NBA*4 = 613,872
    ushort* g64    = (ushort*)(ws + 16000000);   // 12,800,000 (layer 2-3 fused out)
    ushort* g      = (ushort*)(ws + 41600000);   // 25,600,000 (gemm1 out)
    ushort* sbuf   = (ushort*)(ws + 67200000);   // 25,600,000  (total 92.8MB)

    // tmp aliases sbuf (dead until spmmg1 writes it; binB in fusedB completes first).
    int2* tmp = (int2*)sbuf;                     // NBA*EPB*8 = 12,845,056 <= 25.6MB

    // 1) CSR phase A + weight converts (wcvt rides on idle CUs: 196+16 blocks)
    hipLaunchKernelGGL(binA_k, dim3(NBA + 16), dim3(1024), 0, stream,
                       row, col, vals, tmp, offT, W1, W2, W3, Wt1, Wt2, Wt3);

    const int GEMM_GRID = (N_NODES + 63) / 64;     // 1563
    const int SPMM_GRID = N_NODES / 16;            // 6250 (exact)

    // 2) fused: CSR phase B (blocks 0..781) + layer-1 GEMM (blocks 782..2344)
    hipLaunchKernelGGL(fusedB_k, dim3(NBK + GEMM_GRID), dim3(256), 0, stream,
                       tmp, offT, rowptr, ep, x, Wt1, b1, g);

    // 3) spmm1 + gemm2 fused (reads g, writes sbuf — tmp dead now)
    hipLaunchKernelGGL((spmmg_k<128>), dim3(SPMM_GRID), dim3(256), 0, stream,
                       rowptr, ep, g, Wt2, b2, sbuf);
    // 4) spmm2 + gemm3 fused
    hipLaunchKernelGGL((spmmg_k<64>), dim3(SPMM_GRID), dim3(256), 0, stream,
                       rowptr, ep, sbuf, Wt3, b3, g64);
    // 5) spmm3 (final, fp32 out)
    hipLaunchKernelGGL(spmm64_k, dim3(SPMM_GRID), dim3(256), 0, stream,
                       rowptr, ep, g64, out);
}

// Round 16
// 238.514 us; speedup vs baseline: 1.2411x; 1.0037x over previous
//
#include <hip/hip_runtime.h>

#define N_NODES 100000
#define N_EDGES 1600000

#define NBK 782    // row buckets of 128 rows: ceil(100000/128)
#define EPB 8192   // edges per binA block
#define NBA 196    // binA blocks: 196*8192 = 1,605,632 >= N_EDGES
#define CAPE 2688  // LDS edge-stage cap in binB (bucket mean 2048, sigma 45 -> 14σ)

typedef __attribute__((ext_vector_type(8))) short short8;
typedef __attribute__((ext_vector_type(4))) float f32x4;

__device__ __forceinline__ ushort f2bf(float f) {
    uint u = __float_as_uint(f);
    return (ushort)((u + 0x7fff + ((u >> 16) & 1)) >> 16);   // RNE
}
__device__ __forceinline__ float bflo(uint p) { return __uint_as_float(p << 16); }
__device__ __forceinline__ float bfhi(uint p) { return __uint_as_float(p & 0xffff0000u); }

// ---------------- CSR build: two-pass counting sort ----------------------------------
// Phase A: by 128-row bucket; single-pass rank trick. Phase B: within each bucket,
// sort by (row, col>>14) — 1024 bins — so each row's edge list is COLUMN-ORDERED.
// Column-ordered walks make all concurrent spmm blocks sweep X low->high in phase:
// the instantaneous working set fits each XCD's 4MB L2 (vs 25.6MB random), cutting
// the 7x L2-miss re-fetch amplification (FETCH 180MB per spmm pass).

__device__ void binA_body(int bid, const int* __restrict__ row,
                          const int* __restrict__ col, const float* __restrict__ vals,
                          int2* __restrict__ tmp, int* __restrict__ offT) {
    __shared__ int cnt[NBK];
    __shared__ int exo[NBK];
    __shared__ int wpart[16];
    int t = threadIdx.x;
    int lane = t & 63;
    int base = bid * EPB;

    // stage 8 edges/thread in registers (row/col/vals each read exactly once)
    int rr[8], cc[8], rk[8];
    float vv[8];
#pragma unroll
    for (int u = 0; u < 8; ++u) {
        int e = base + u * 1024 + t;
        bool ok = (e < N_EDGES);
        rr[u] = ok ? row[e] : -1;
        cc[u] = ok ? col[e] : 0;
        vv[u] = ok ? vals[e] : 0.f;
    }

    if (t < NBK) cnt[t] = 0;
    __syncthreads();
#pragma unroll
    for (int u = 0; u < 8; ++u)
        if (rr[u] >= 0) rk[u] = atomicAdd(&cnt[rr[u] >> 7], 1);   // rank + histogram
    __syncthreads();
    int hv = (t < NBK) ? cnt[t] : 0;

    // wave-shuffle inclusive scan over thread order (cnt is zero past NBK)
    int v = hv;
    for (int off = 1; off < 64; off <<= 1) {
        int u2 = __shfl_up(v, off);
        if (lane >= off) v += u2;
    }
    if (lane == 63) wpart[t >> 6] = v;
    __syncthreads();
    if (t == 0) {
        int acc = 0;
#pragma unroll
        for (int i = 0; i < 16; ++i) { int w = wpart[i]; wpart[i] = acc; acc += w; }
    }
    __syncthreads();
    v += wpart[t >> 6];                      // inclusive prefix over cnt[0..t]
    if (t < NBK) {
        int ex = v - hv;
        exo[t] = ex;
        offT[t * NBA + bid] = ex;
    }
    if (t == NBK - 1) offT[NBK * NBA + bid] = v;  // row NBK = edges in block
    __syncthreads();
    // scatter into block-private region, grouped by bucket — NO atomics
#pragma unroll
    for (int u = 0; u < 8; ++u) {
        if (rr[u] >= 0) {
            int p = exo[rr[u] >> 7] + rk[u];
            int2 w;
            w.x = ((rr[u] & 127) << 17) | cc[u];   // 7-bit row-in-bucket | 17-bit col
            w.y = __float_as_int(vv[u]);
            tmp[base + p] = w;
        }
    }
}

__device__ void wcvt_body(int bid, const float* __restrict__ W1,
                          const float* __restrict__ W2, const float* __restrict__ W3,
                          ushort* __restrict__ Wt1, ushort* __restrict__ Wt2,
                          ushort* __restrict__ Wt3) {
    int i = bid * 1024 + threadIdx.x;        // 16 blocks x 1024 = 16384
    if (i < 16384) {
        int n = i >> 7, k = i & 127;
        Wt1[i] = f2bf(W1[k * 128 + n]);
        Wt2[i] = f2bf(W2[k * 128 + n]);
    }
    if (i < 8192) {
        int n = i >> 7, k = i & 127;
        Wt3[i] = f2bf(W3[k * 64 + n]);
    }
}

__global__ void __launch_bounds__(1024) binA_k(const int* __restrict__ row,
                                               const int* __restrict__ col,
                                               const float* __restrict__ vals,
                                               int2* __restrict__ tmp,
                                               int* __restrict__ offT,
                                               const float* __restrict__ W1,
                                               const float* __restrict__ W2,
                                               const float* __restrict__ W3,
                                               ushort* __restrict__ Wt1,
                                               ushort* __restrict__ Wt2,
                                               ushort* __restrict__ Wt3) {
    if (blockIdx.x < NBA)
        binA_body(blockIdx.x, row, col, vals, tmp, offT);
    else
        wcvt_body(blockIdx.x - NBA, W1, W2, W3, Wt1, Wt2, Wt3);
}

// Phase B body: one block per bucket. bstart[b] = sum_s offT[b][s] (offT[0][s]==0).
// 16-lane group per segment loads coalesced; counting sort over 1024 (row,shard)
// bins — bin = e.x >> 14 = (rib<<3)|(col>>14). Pass 2 scatters (row,col)-ordered.

__device__ void binB_body(int b, const int2* __restrict__ tmp,
                          const int* __restrict__ offT, int* __restrict__ rowptr,
                          int2* __restrict__ ep) {
    __shared__ int goff[NBA];
    __shared__ int scnt[NBA];
    __shared__ int sdst[NBA];
    __shared__ int h[1024];
    __shared__ int2 ebuf[CAPE];
    __shared__ int wpart[4];
    __shared__ int wq[4];
    int t = threadIdx.x;
    int lane = t & 63;

    int o0 = 0, c = 0;
    if (t < NBA) {
        o0 = offT[b * NBA + t];
        int o1 = offT[(b + 1) * NBA + t];
        c = o1 - o0;
        goff[t] = t * EPB + o0;
        scnt[t] = c;
    }
    // bstart[b] = sum_s offT[b*NBA+s] (wave reduce of o0; zero past NBA)
    int part = o0;
#pragma unroll
    for (int off = 1; off < 64; off <<= 1) part += __shfl_xor(part, off);
    if (lane == 0) wq[t >> 6] = part;
    if (b == 0 && t == 0) rowptr[N_NODES] = N_EDGES;

    // exclusive scan of segment counts (wave shuffle, 256 threads)
    int v = c;
    for (int off = 1; off < 64; off <<= 1) {
        int u = __shfl_up(v, off);
        if (lane >= off) v += u;
    }
    if (lane == 63) wpart[t >> 6] = v;
    for (int i = t; i < 1024; i += 256) h[i] = 0;
    __syncthreads();
    if (t == 0) {
        int acc = 0;
#pragma unroll
        for (int i = 0; i < 4; ++i) { int w = wpart[i]; wpart[i] = acc; acc += w; }
    }
    __syncthreads();
    v += wpart[t >> 6];
    if (t < NBA) sdst[t] = v - c;
    __syncthreads();

    // pass 1: 16-lane group per segment: coalesced load, 1024-bin LDS hist, pack
    int grp = t >> 4, gl = t & 15;            // 16 groups of 16 lanes
    for (int s = grp; s < NBA; s += 16) {
        int n = scnt[s], go = goff[s], dd = sdst[s];
        for (int i = gl; i < n; i += 16) {
            int2 e = tmp[go + i];
            atomicAdd(&h[e.x >> 14], 1);      // bin = (rib<<3)|(col>>14), < 1024
            ebuf[dd + i] = e;
        }
    }
    __syncthreads();
    // exclusive scan over 1024 bins: 4 bins/thread + 256-wide shuffle scan
    int h0 = h[4 * t], h1 = h[4 * t + 1], h2 = h[4 * t + 2], h3 = h[4 * t + 3];
    int st = h0 + h1 + h2 + h3;
    int sv = st;
    for (int off = 1; off < 64; off <<= 1) {
        int u = __shfl_up(sv, off);
        if (lane >= off) sv += u;
    }
    if (lane == 63) wpart[t >> 6] = sv;
    __syncthreads();
    if (t == 0) {
        int acc = 0;
#pragma unroll
        for (int i = 0; i < 4; ++i) { int w = wpart[i]; wpart[i] = acc; acc += w; }
    }
    __syncthreads();
    sv += wpart[t >> 6];
    int basex = sv - st;                      // exclusive offset of bin 4t
    h[4 * t]     = basex;
    h[4 * t + 1] = basex + h0;
    h[4 * t + 2] = basex + h0 + h1;
    h[4 * t + 3] = basex + h0 + h1 + h2;
    int bs = wq[0] + wq[1] + wq[2] + wq[3];
    __syncthreads();
    if (t < 128) {
        int r = (b << 7) + t;
        if (r < N_NODES) rowptr[r] = bs + h[t << 3];   // row base = its shard-0 bin
    }
    __syncthreads();
    // pass 2: scatter from packed ebuf; h[] doubles as the bin cursors
    int T = sdst[NBA - 1] + scnt[NBA - 1];
    for (int j = t; j < T; j += 256) {
        int2 e = ebuf[j];
        int p = atomicAdd(&h[e.x >> 14], 1);
        int2 w;
        w.x = e.x & 0x1ffff;
        w.y = e.y;
        ep[bs + p] = w;
    }
}

// layer-1 GEMM body (fp32 A converted in-register; 64 rows/block, 256 threads).

__device__ void gemm1_body(int bid, const float* __restrict__ Xf,
                           const ushort* __restrict__ Wt,
                           const float* __restrict__ bias, ushort* __restrict__ Y) {
    int wv = threadIdx.x >> 6;
    int l = threadIdx.x & 63;
    int lg = l >> 4, lm = l & 15;
    int rbase = bid * 64 + wv * 16;

    int arow = rbase + lm;
    if (arow > N_NODES - 1) arow = N_NODES - 1;     // clamp (stores predicated)

    f32x4 acc[8];
#pragma unroll
    for (int n = 0; n < 8; n++) acc[n] = (f32x4){0.f, 0.f, 0.f, 0.f};

#pragma unroll
    for (int kk = 0; kk < 4; ++kk) {
        const float* ap = Xf + (size_t)arow * 128 + kk * 32 + lg * 8;
        float4 u = *(const float4*)ap;
        float4 v = *(const float4*)(ap + 4);
        short8 a = (short8){(short)f2bf(u.x), (short)f2bf(u.y), (short)f2bf(u.z),
                            (short)f2bf(u.w), (short)f2bf(v.x), (short)f2bf(v.y),
                            (short)f2bf(v.z), (short)f2bf(v.w)};
#pragma unroll
        for (int n = 0; n < 8; ++n) {
            short8 b = *(const short8*)(Wt + (size_t)(n * 16 + lm) * 128 + kk * 32 + lg * 8);
            acc[n] = __builtin_amdgcn_mfma_f32_16x16x32_bf16(a, b, acc[n], 0, 0, 0);
        }
    }

    int r0 = rbase + lg * 4;
#pragma unroll
    for (int n = 0; n < 8; ++n) {
        int c = n * 16 + lm;
        float bj = bias[c];
#pragma unroll
        for (int i = 0; i < 4; ++i) {
            int r = r0 + i;
            if (r < N_NODES) Y[(size_t)r * 128 + c] = f2bf(acc[n][i] + bj);
        }
    }
}

// fused 256-thread dispatch: blocks [0,NBK) run binB; [NBK, NBK+1563) run gemm1.
__global__ void __launch_bounds__(256) fusedB_k(const int2* __restrict__ tmp,
                                                const int* __restrict__ offT,
                                                int* __restrict__ rowptr,
                                                int2* __restrict__ ep,
                                                const float* __restrict__ x,
                                                const ushort* __restrict__ Wt1,
                                                const float* __restrict__ b1,
                                                ushort* __restrict__ g) {
    if (blockIdx.x < NBK)
        binB_body(blockIdx.x, tmp, offT, rowptr, ep);
    else
        gemm1_body(blockIdx.x - NBK, x, Wt1, b1, g);
}

// ---------------- SpMM+GEMM fused (layers 1-2 and 2-3) -------------------------------

#define SPMMG_P1(EPREAD)                                                      \
    {                                                                         \
        const uint4* xp = (const uint4*)xb;                                   \
        float a0 = 0.f, a1 = 0.f, a2 = 0.f, a3 = 0.f;                         \
        float a4 = 0.f, a5 = 0.f, a6 = 0.f, a7 = 0.f;                         \
        int i = s;                                                            \
        for (; i + 4 <= e; i += 4) {                                          \
            int2 e0 = EPREAD(i), e1 = EPREAD(i + 1);                          \
            int2 e2 = EPREAD(i + 2), e3 = EPREAD(i + 3);                      \
            uint4 x0 = xp[e0.x * 16 + hl];                                    \
            uint4 x1 = xp[e1.x * 16 + hl];                                    \
            uint4 x2 = xp[e2.x * 16 + hl];                                    \
            uint4 x3 = xp[e3.x * 16 + hl];                                    \
            float v0 = __int_as_float(e0.y), v1 = __int_as_float(e1.y);       \
            float v2 = __int_as_float(e2.y), v3 = __int_as_float(e3.y);       \
            a0 = fmaf(v0, bflo(x0.x), a0); a1 = fmaf(v0, bfhi(x0.x), a1);     \
            a2 = fmaf(v0, bflo(x0.y), a2); a3 = fmaf(v0, bfhi(x0.y), a3);     \
            a4 = fmaf(v0, bflo(x0.z), a4); a5 = fmaf(v0, bfhi(x0.z), a5);     \
            a6 = fmaf(v0, bflo(x0.w), a6); a7 = fmaf(v0, bfhi(x0.w), a7);     \
            a0 = fmaf(v1, bflo(x1.x), a0); a1 = fmaf(v1, bfhi(x1.x), a1);     \
            a2 = fmaf(v1, bflo(x1.y), a2); a3 = fmaf(v1, bfhi(x1.y), a3);     \
            a4 = fmaf(v1, bflo(x1.z), a4); a5 = fmaf(v1, bfhi(x1.z), a5);     \
            a6 = fmaf(v1, bflo(x1.w), a6); a7 = fmaf(v1, bfhi(x1.w), a7);     \
            a0 = fmaf(v2, bflo(x2.x), a0); a1 = fmaf(v2, bfhi(x2.x), a1);     \
            a2 = fmaf(v2, bflo(x2.y), a2); a3 = fmaf(v2, bfhi(x2.y), a3);     \
            a4 = fmaf(v2, bflo(x2.z), a4); a5 = fmaf(v2, bfhi(x2.z), a5);     \
            a6 = fmaf(v2, bflo(x2.w), a6); a7 = fmaf(v2, bfhi(x2.w), a7);     \
            a0 = fmaf(v3, bflo(x3.x), a0); a1 = fmaf(v3, bfhi(x3.x), a1);     \
            a2 = fmaf(v3, bflo(x3.y), a2); a3 = fmaf(v3, bfhi(x3.y), a3);     \
            a4 = fmaf(v3, bflo(x3.z), a4); a5 = fmaf(v3, bfhi(x3.z), a5);     \
            a6 = fmaf(v3, bflo(x3.w), a6); a7 = fmaf(v3, bfhi(x3.w), a7);     \
        }                                                                     \
        for (; i < e; ++i) {                                                  \
            int2 e0 = EPREAD(i);                                              \
            uint4 x0 = xp[e0.x * 16 + hl];                                    \
            float v0 = __int_as_float(e0.y);                                  \
            a0 = fmaf(v0, bflo(x0.x), a0); a1 = fmaf(v0, bfhi(x0.x), a1);     \
            a2 = fmaf(v0, bflo(x0.y), a2); a3 = fmaf(v0, bfhi(x0.y), a3);     \
            a4 = fmaf(v0, bflo(x0.z), a4); a5 = fmaf(v0, bfhi(x0.z), a5);     \
            a6 = fmaf(v0, bflo(x0.w), a6); a7 = fmaf(v0, bfhi(x0.w), a7);     \
        }                                                                     \
        a0 = fmaxf(a0, 0.f); a1 = fmaxf(a1, 0.f);                             \
        a2 = fmaxf(a2, 0.f); a3 = fmaxf(a3, 0.f);                             \
        a4 = fmaxf(a4, 0.f); a5 = fmaxf(a5, 0.f);                             \
        a6 = fmaxf(a6, 0.f); a7 = fmaxf(a7, 0.f);                             \
        uint4 o;                                                              \
        o.x = (uint)f2bf(a0) | ((uint)f2bf(a1) << 16);                        \
        o.y = (uint)f2bf(a2) | ((uint)f2bf(a3) << 16);                        \
        o.z = (uint)f2bf(a4) | ((uint)f2bf(a5) << 16);                        \
        o.w = (uint)f2bf(a6) | ((uint)f2bf(a7) << 16);                        \
        xl4[g * 17 + hl] = o;                                                 \
    }

template <int DNO>
__global__ void __launch_bounds__(256) spmmg_k(const int* __restrict__ rowptr,
                                               const int2* __restrict__ ep,
                                               const ushort* __restrict__ xb,
                                               const ushort* __restrict__ Wt,
                                               const float* __restrict__ bias,
                                               ushort* __restrict__ Y) {
    constexpr int CAP = 1536;                  // 12 KB LDS; block mean = 256 edges
    __shared__ int2 eb[CAP];
    __shared__ uint4 xl4[16 * 17];             // 16 rows x 128 bf16, pitch 136 (4.35KB)
    __shared__ int sh_s0, sh_n;
    int t = threadIdx.x;
    int g = t >> 4, hl = t & 15;
    int rbase = blockIdx.x * 16;               // 6250*16 == N_NODES exactly

    if (t == 0) {
        int s0 = rowptr[rbase];
        sh_s0 = s0;
        sh_n = rowptr[rbase + 16] - s0;
    }
    __syncthreads();
    int s0 = sh_s0, n = sh_n;
    bool inlds = (n <= CAP);
    if (inlds) {
        for (int j = t; j < n; j += 256) eb[j] = ep[s0 + j];   // coalesced stage
    }
    __syncthreads();
    int s = rowptr[rbase + g], e = rowptr[rbase + g + 1];

    if (inlds) {
        s -= s0; e -= s0;
#define EPL(i) eb[i]
        SPMMG_P1(EPL)
#undef EPL
    } else {                                   // overflow fallback (rare)
#define EPG(i) ep[i]
        SPMMG_P1(EPG)
#undef EPG
    }
    __syncthreads();

    // Phase 2: GEMM epilogue on the LDS tile (proven gemm_k fragment mapping)
    constexpr int TPW = DNO / 64;              // col-tiles per wave (2 or 1)
    const ushort* xl = (const ushort*)xl4;
    int wv = t >> 6;
    int l = t & 63;
    int lg = l >> 4, lm = l & 15;
#pragma unroll
    for (int tt = 0; tt < TPW; ++tt) {
        int ct = wv * TPW + tt;
        f32x4 acc = (f32x4){0.f, 0.f, 0.f, 0.f};
#pragma unroll
        for (int kk = 0; kk < 4; ++kk) {
            short8 a = *(const short8*)(xl + lm * 136 + kk * 32 + lg * 8);
            short8 b = *(const short8*)(Wt + (size_t)(ct * 16 + lm) * 128 + kk * 32 + lg * 8);
            acc = __builtin_amdgcn_mfma_f32_16x16x32_bf16(a, b, acc, 0, 0, 0);
        }
        int c = ct * 16 + lm;
        float bj = bias[c];
        int r0 = rbase + lg * 4;
#pragma unroll
        for (int i = 0; i < 4; ++i) {
            int r = r0 + i;
            if (r < N_NODES) Y[(size_t)r * DNO + c] = f2bf(acc[i] + bj);
        }
    }
}

// ---------------- SpMM final (D=64 in, fp32 out, no relu) ----------------------------

__global__ void __launch_bounds__(256) spmm64_k(const int* __restrict__ rowptr,
                                                const int2* __restrict__ ep,
                                                const ushort* __restrict__ xb,
                                                float* __restrict__ y) {
    constexpr int CAP = 1536;
    __shared__ int2 eb[CAP];
    __shared__ int sh_s0, sh_n;
    int t = threadIdx.x;
    int g = t >> 4, hl = t & 15;
    int rbase = blockIdx.x * 16;
    int w = rbase + g;

    if (t == 0) {
        int s0 = rowptr[rbase];
        sh_s0 = s0;
        sh_n = rowptr[rbase + 16] - s0;
    }
    __syncthreads();
    int s0 = sh_s0, n = sh_n;
    bool inlds = (n <= CAP);
    if (inlds) {
        for (int j = t; j < n; j += 256) eb[j] = ep[s0 + j];
    }
    __syncthreads();
    int s = rowptr[w], e = rowptr[w + 1];

    const uint2* xp = (const uint2*)xb;        // row stride 16 uint2
    float a0 = 0.f, a1 = 0.f, a2 = 0.f, a3 = 0.f;

#define S64_BODY(EPREAD)                                                      \
    {                                                                         \
        int i = s;                                                            \
        for (; i + 4 <= e; i += 4) {                                          \
            int2 e0 = EPREAD(i), e1 = EPREAD(i + 1);                          \
            int2 e2 = EPREAD(i + 2), e3 = EPREAD(i + 3);                      \
            uint2 x0 = xp[e0.x * 16 + hl];                                    \
            uint2 x1 = xp[e1.x * 16 + hl];                                    \
            uint2 x2 = xp[e2.x * 16 + hl];                                    \
            uint2 x3 = xp[e3.x * 16 + hl];                                    \
            float v0 = __int_as_float(e0.y), v1 = __int_as_float(e1.y);       \
            float v2 = __int_as_float(e2.y), v3 = __int_as_float(e3.y);       \
            a0 = fmaf(v0, bflo(x0.x), a0); a1 = fmaf(v0, bfhi(x0.x), a1);     \
            a2 = fmaf(v0, bflo(x0.y), a2); a3 = fmaf(v0, bfhi(x0.y), a3);     \
            a0 = fmaf(v1, bflo(x1.x), a0); a1 = fmaf(v1, bfhi(x1.x), a1);     \
            a2 = fmaf(v1, bflo(x1.y), a2); a3 = fmaf(v1, bfhi(x1.y), a3);     \
            a0 = fmaf(v2, bflo(x2.x), a0); a1 = fmaf(v2, bfhi(x2.x), a1);     \
            a2 = fmaf(v2, bflo(x2.y), a2); a3 = fmaf(v2, bfhi(x2.y), a3);     \
            a0 = fmaf(v3, bflo(x3.x), a0); a1 = fmaf(v3, bfhi(x3.x), a1);     \
            a2 = fmaf(v3, bflo(x3.y), a2); a3 = fmaf(v3, bfhi(x3.y), a3);     \
        }                                                                     \
        for (; i < e; ++i) {                                                  \
            int2 e0 = EPREAD(i);                                              \
            uint2 x0 = xp[e0.x * 16 + hl];                                    \
            float v0 = __int_as_float(e0.y);                                  \
            a0 = fmaf(v0, bflo(x0.x), a0); a1 = fmaf(v0, bfhi(x0.x), a1);     \
            a2 = fmaf(v0, bflo(x0.y), a2); a3 = fmaf(v0, bfhi(x0.y), a3);     \
        }                                                                     \
    }

    if (inlds) {
        s -= s0; e -= s0;
#define EPL(i) eb[i]
        S64_BODY(EPL)
#undef EPL
    } else {
#define EPG(i) ep[i]
        S64_BODY(EPG)
#undef EPG
    }
#undef S64_BODY
    float4 o; o.x = a0; o.y = a1; o.z = a2; o.w = a3;
    ((float4*)y)[w * 16 + hl] = o;             // final output fp32
}

// ---------------- launch ----------------

extern "C" void kernel_launch(void* const* d_in, const int* in_sizes, int n_in,
                              void* d_out, int out_size, void* d_ws, size_t ws_size,
                              hipStream_t stream) {
    const float* x    = (const float*)d_in[0];
    const float* vals = (const float*)d_in[1];
    const float* W1   = (const float*)d_in[2];
    const float* b1   = (const float*)d_in[3];
    const float* W2   = (const float*)d_in[4];
    const float* b2   = (const float*)d_in[5];
    const float* W3   = (const float*)d_in[6];
    const float* b3   = (const float*)d_in[7];
    const int* row    = (const int*)d_in[8];
    const int* col    = (const int*)d_in[9];
    float* out = (float*)d_out;

    char* ws = (char*)d_ws;
    int2*   ep     = (int2*)  (ws + 0);          // 12,800,000
    int*    rowptr = (int*)   (ws + 12800000);   // 400,004
    ushort* Wt1    = (ushort*)(ws + 13601024);   // 32,768
    ushort* Wt2    = (ushort*)(ws + 13633792);   // 32,768
    ushort* Wt3    = (ushort*)(ws + 13666560);   // 16,384
    int*    offT   = (int*)   (ws + 13700096);   // (NBK+1)*NBA*4 = 613,872
    ushort* g64    = (ushort*)(ws + 16000000);   // 12,800,000 (layer 2-3 fused out)
    ushort* g      = (ushort*)(ws + 41600000);   // 25,600,000 (gemm1 out)
    ushort* sbuf   = (ushort*)(ws + 67200000);   // 25,600,000  (total 92.8MB)

    // tmp aliases sbuf (dead until spmmg1 writes it; binB in fusedB completes first).
    int2* tmp = (int2*)sbuf;                     // NBA*EPB*8 = 12,845,056 <= 25.6MB

    // 1) CSR phase A + weight converts (wcvt rides on idle CUs: 196+16 blocks)
    hipLaunchKernelGGL(binA_k, dim3(NBA + 16), dim3(1024), 0, stream,
                       row, col, vals, tmp, offT, W1, W2, W3, Wt1, Wt2, Wt3);

    const int GEMM_GRID = (N_NODES + 63) / 64;     // 1563
    const int SPMM_GRID = N_NODES / 16;            // 6250 (exact)

    // 2) fused: CSR phase B (blocks 0..781, col-ordered sort) + layer-1 GEMM
    hipLaunchKernelGGL(fusedB_k, dim3(NBK + GEMM_GRID), dim3(256), 0, stream,
                       tmp, offT, rowptr, ep, x, Wt1, b1, g);

    // 3) spmm1 + gemm2 fused (reads g, writes sbuf — tmp dead now)
    hipLaunchKernelGGL((spmmg_k<128>), dim3(SPMM_GRID), dim3(256), 0, stream,
                       rowptr, ep, g, Wt2, b2, sbuf);
    // 4) spmm2 + gemm3 fused
    hipLaunchKernelGGL((spmmg_k<64>), dim3(SPMM_GRID), dim3(256), 0, stream,
                       rowptr, ep, sbuf, Wt3, b3, g64);
    // 5) spmm3 (final, fp32 out)
    hipLaunchKernelGGL(spmm64_k, dim3(SPMM_GRID), dim3(256), 0, stream,
                       rowptr, ep, g64, out);
}